// Round 4
// baseline (1702.009 us; speedup 1.0000x reference)
//
#include <hip/hip_runtime.h>

// RGCN: 3× HeteroGraphConv(mean over R=4 relations of GraphConv(norm='both')).
// R4: (a) gather fused INTO the MFMA GEMM (gconv): per 64-row tile, per rel:
// CSR-gather -> rs_in-folded hi/lo fp16 LDS tile -> K=128 MFMA -> bias+relu
// into register out-acc; h written once (no Ahi/Alo arrays, no RMW, no memsets).
// (b) edge_hist -> LDS range-partitioned histogram (plain stores, no atomics).

#define NNODES 100000
#define NEDGE  400000
#define NREL   4
#define DHID   128
#define NCLS   16
#define SCANB  98            // ceil(N / 1024)
#define HR     64            // histogram node ranges
#define HW     1563          // ceil(N / HR)

typedef _Float16 f16x8 __attribute__((ext_vector_type(8)));
typedef float    f32x4 __attribute__((ext_vector_type(4)));

// ---------------- LDS-partitioned degree histogram (no global atomics) ----------------
__global__ __launch_bounds__(512) void hist_lds(const int* __restrict__ src,
                                                const int* __restrict__ dst,
                                                int* __restrict__ cnt_out,
                                                int* __restrict__ cnt_in) {
    __shared__ int co[HW], ci[HW];
    int r = blockIdx.y, g = blockIdx.x;
    int lo = g * HW;
    int hi = min(lo + HW, NNODES);
    for (int t = threadIdx.x; t < HW; t += 512) { co[t] = 0; ci[t] = 0; }
    __syncthreads();
    const int* S = src + (size_t)r * NEDGE;
    const int* D = dst + (size_t)r * NEDGE;
    for (int e = threadIdx.x; e < NEDGE; e += 512) {
        int s = S[e];
        if (s >= lo && s < hi) atomicAdd(&co[s - lo], 1);
        int d = D[e];
        if (d >= lo && d < hi) atomicAdd(&ci[d - lo], 1);
    }
    __syncthreads();
    for (int t = threadIdx.x; t < HW && lo + t < NNODES; t += 512) {
        cnt_out[(size_t)r * NNODES + lo + t] = co[t];
        cnt_in [(size_t)r * NNODES + lo + t] = ci[t];
    }
}

__global__ void rs_fin(const int* __restrict__ cnt_out, const int* __restrict__ cnt_in,
                       float* __restrict__ rs_out, float* __restrict__ rs_in) {
    int i = blockIdx.x * 256 + threadIdx.x;
    if (i < NREL * NNODES) {
        rs_out[i] = rsqrtf(fmaxf((float)cnt_out[i], 1.0f));
        rs_in [i] = rsqrtf(fmaxf((float)cnt_in [i], 1.0f));
    }
}

// ---------------- 2-level exclusive scan of cnt_in -> ofs ----------------
__global__ void scan1(const int* __restrict__ cnt, int* __restrict__ part) {
    __shared__ int sh[256];
    int r = blockIdx.y, b = blockIdx.x, tid = threadIdx.x;
    int n0 = b * 1024 + tid * 4;
    int s = 0;
#pragma unroll
    for (int j = 0; j < 4; ++j) {
        int n = n0 + j;
        s += (n < NNODES) ? cnt[r * NNODES + n] : 0;
    }
    sh[tid] = s; __syncthreads();
    for (int off = 128; off > 0; off >>= 1) {
        if (tid < off) sh[tid] += sh[tid + off];
        __syncthreads();
    }
    if (tid == 0) part[r * SCANB + b] = sh[0];
}

__global__ void scan2(int* __restrict__ part) {
    __shared__ int sh[128];
    int r = blockIdx.x, tid = threadIdx.x;
    int v = (tid < SCANB) ? part[r * SCANB + tid] : 0;
    sh[tid] = v; __syncthreads();
    for (int off = 1; off < 128; off <<= 1) {
        int t = (tid >= off) ? sh[tid - off] : 0;
        __syncthreads();
        sh[tid] += t;
        __syncthreads();
    }
    if (tid < SCANB) part[r * SCANB + tid] = sh[tid] - v;  // exclusive
}

__global__ void scan3(const int* __restrict__ cnt, const int* __restrict__ part,
                      int* __restrict__ ofs) {
    __shared__ int sh[256];
    int r = blockIdx.y, b = blockIdx.x, tid = threadIdx.x;
    int n0 = b * 1024 + tid * 4;
    int v[4];
    int tsum = 0;
#pragma unroll
    for (int j = 0; j < 4; ++j) {
        int n = n0 + j;
        v[j] = (n < NNODES) ? cnt[r * NNODES + n] : 0;
        tsum += v[j];
    }
    sh[tid] = tsum; __syncthreads();
    for (int off = 1; off < 256; off <<= 1) {
        int t = (tid >= off) ? sh[tid - off] : 0;
        __syncthreads();
        sh[tid] += t;
        __syncthreads();
    }
    int base = part[r * SCANB + b] + sh[tid] - tsum;
#pragma unroll
    for (int j = 0; j < 4; ++j) {
        int n = n0 + j;
        if (n < NNODES) ofs[r * (NNODES + 1) + n] = base;
        base += v[j];
    }
    if (b == 0 && tid == 0) ofs[r * (NNODES + 1) + NNODES] = NEDGE;
}

__global__ void csr_fill(const int* __restrict__ src, const int* __restrict__ dst,
                         const int* __restrict__ ofs, int* __restrict__ cnt_in,
                         int* __restrict__ csr) {
    int e = blockIdx.x * 256 + threadIdx.x;
    int r = blockIdx.y;
    if (e < NEDGE) {
        int s = src[r * NEDGE + e], d = dst[r * NEDGE + e];
        int k = atomicSub(&cnt_in[r * NNODES + d], 1) - 1;
        csr[(size_t)r * NEDGE + ofs[r * (NNODES + 1) + d] + k] = s;
    }
}

// ---------------- W pre-split into MFMA frag layout ----------------
// Wt[((r*16 + k>>3)*128 + c)*8 + (k&7)], value W[r][k][c] split hi/lo.
__global__ void wsplit(const float* __restrict__ W, _Float16* __restrict__ whi,
                       _Float16* __restrict__ wlo) {
    int idx = blockIdx.x * 256 + threadIdx.x;   // 4*128*128 = 65536
    int c = idx & 127, k = (idx >> 7) & 127, r = idx >> 14;
    float w = W[(size_t)r * 16384 + k * 128 + c];
    _Float16 hi = (_Float16)w;
    size_t o = (((size_t)r * 16 + (k >> 3)) * 128 + c) * 8 + (k & 7);
    whi[o] = hi;
    wlo[o] = (_Float16)(w - (float)hi);
}

// ---------------- fused GraphConv layer: gather + MFMA + epilogue ----------------
// Per 64-row tile: for each rel r: agg rows -> LDS (hi/lo fp16, rs_in folded),
// MFMA K=128 vs Wt_r, oacc += relu(acc + b_r). Write h = oacc * 0.25 once.
__global__ __launch_bounds__(512) void gconv(
        const float* __restrict__ H, const float* __restrict__ rs_out,
        const float* __restrict__ rs_in, const int* __restrict__ ofs,
        const int* __restrict__ csr, const _Float16* __restrict__ Wt_hi,
        const _Float16* __restrict__ Wt_lo, const float* __restrict__ bias,
        float* __restrict__ outH) {
    __shared__ _Float16 lhi[16 * 67 * 8];   // [kblock][row(64)+skew][8], 17.2KB
    __shared__ _Float16 llo[16 * 67 * 8];
    __shared__ int lofs[65];
    int tid = threadIdx.x;
    int lane = tid & 63, wid = tid >> 6;
    int wm = wid >> 2, wn = wid & 3;        // 2x4 waves: wave tile 32 rows x 32 cols
    int r15 = lane & 15;
    int row0 = blockIdx.x * 64;

    f32x4 oacc[2][2] = {};

    for (int r = 0; r < NREL; ++r) {
        if (tid < 65) {
            int n = row0 + tid;
            lofs[tid] = (n <= NNODES) ? ofs[r * (NNODES + 1) + n] : NEDGE;
        }
        __syncthreads();   // lofs ready; prev rel's MFMA reads done -> LDS reusable

        // --- gather phase: 4 rows per iteration across 512 threads ---
        {
            int j = tid & 127;                       // feature (= k index)
            const int*   cs  = csr    + (size_t)r * NEDGE;
            const float* rso = rs_out + (size_t)r * NNODES;
            const float* rsi = rs_in  + (size_t)r * NNODES;
            for (int rr = (tid >> 7); rr < 64; rr += 4) {
                int row = row0 + rr;
                float acc = 0.f;
                if (row < NNODES) {
                    int i = lofs[rr], end = lofs[rr + 1];
                    for (; i + 4 <= end; i += 4) {
                        int s0 = cs[i], s1 = cs[i + 1], s2 = cs[i + 2], s3 = cs[i + 3];
                        acc += H[(size_t)s0 * DHID + j] * rso[s0]
                             + H[(size_t)s1 * DHID + j] * rso[s1]
                             + H[(size_t)s2 * DHID + j] * rso[s2]
                             + H[(size_t)s3 * DHID + j] * rso[s3];
                    }
                    for (; i < end; ++i) {
                        int s = cs[i];
                        acc += H[(size_t)s * DHID + j] * rso[s];
                    }
                    acc *= rsi[row];
                }
                _Float16 hi = (_Float16)acc;
                int li = ((j >> 3) * 67 + rr) * 8 + (j & 7);
                lhi[li] = hi;
                llo[li] = (_Float16)(acc - (float)hi);
            }
        }
        __syncthreads();

        // --- MFMA phase: K=128 in 4 kt steps ---
        f32x4 acc4[2][2] = {};
        int kb = lane >> 4;                 // k-block within kt
        int rbase = wm * 32 + r15;
#pragma unroll
        for (int kt = 0; kt < 4; ++kt) {
            const _Float16* bh = Wt_hi + ((size_t)r * 16 + kt * 4 + kb) * 128 * 8;
            const _Float16* bl = Wt_lo + ((size_t)r * 16 + kt * 4 + kb) * 128 * 8;
            int c = wn * 32 + r15;
            f16x8 wh[2], wl[2], ah[2], al[2];
#pragma unroll
            for (int nf = 0; nf < 2; ++nf) {
                wh[nf] = *(const f16x8*)(bh + (size_t)(c + nf * 16) * 8);
                wl[nf] = *(const f16x8*)(bl + (size_t)(c + nf * 16) * 8);
            }
#pragma unroll
            for (int mf = 0; mf < 2; ++mf) {
                int li = ((kt * 4 + kb) * 67 + rbase + mf * 16) * 8;
                ah[mf] = *(const f16x8*)&lhi[li];
                al[mf] = *(const f16x8*)&llo[li];
            }
#pragma unroll
            for (int nf = 0; nf < 2; ++nf)
#pragma unroll
                for (int mf = 0; mf < 2; ++mf) {
                    acc4[mf][nf] = __builtin_amdgcn_mfma_f32_16x16x32_f16(ah[mf], wh[nf], acc4[mf][nf], 0, 0, 0);
                    acc4[mf][nf] = __builtin_amdgcn_mfma_f32_16x16x32_f16(ah[mf], wl[nf], acc4[mf][nf], 0, 0, 0);
                    acc4[mf][nf] = __builtin_amdgcn_mfma_f32_16x16x32_f16(al[mf], wh[nf], acc4[mf][nf], 0, 0, 0);
                }
        }

        // --- fold: oacc += relu(acc + bias_r) ---
        const float* b = bias + r * DHID;
#pragma unroll
        for (int mf = 0; mf < 2; ++mf)
#pragma unroll
            for (int nf = 0; nf < 2; ++nf) {
                float bb = b[wn * 32 + nf * 16 + r15];
#pragma unroll
                for (int i = 0; i < 4; ++i)
                    oacc[mf][nf][i] += fmaxf(acc4[mf][nf][i] + bb, 0.f);
            }
    }

    // --- epilogue: C/D layout col=lane&15, row=(lane>>4)*4+i ---
    int rsub = (lane >> 4) * 4;
#pragma unroll
    for (int mf = 0; mf < 2; ++mf)
#pragma unroll
        for (int i = 0; i < 4; ++i) {
            int row = row0 + wm * 32 + mf * 16 + rsub + i;
            if (row < NNODES) {
#pragma unroll
                for (int nf = 0; nf < 2; ++nf) {
                    int c = wn * 32 + nf * 16 + r15;
                    outH[(size_t)row * DHID + c] = oacc[mf][nf][i] * 0.25f;
                }
            }
        }
}

// ---------------- layer 2 (fp32, small): hw = H @ [W2_0|..|W2_3] ----------------
__global__ __launch_bounds__(256) void gemm64(const float* __restrict__ H,
                                              const float* __restrict__ W2,
                                              float* __restrict__ hw) {
    __shared__ float As[64][68];
    __shared__ float Ws[64][68];
    int tid = threadIdx.x;
    int tx = tid & 15, ty = tid >> 4;
    int row0 = blockIdx.x * 64;
    float acc[4][4];
#pragma unroll
    for (int i = 0; i < 4; ++i)
#pragma unroll
        for (int j = 0; j < 4; ++j) acc[i][j] = 0.f;

    for (int kt = 0; kt < 2; ++kt) {
        int k0 = kt * 64;
#pragma unroll
        for (int i = 0; i < 16; ++i) {
            int idx = tid + i * 256;
            int rr = idx >> 6, kk = idx & 63;
            int row = row0 + rr;
            As[rr][kk] = (row < NNODES) ? H[(size_t)row * DHID + k0 + kk] : 0.f;
        }
#pragma unroll
        for (int i = 0; i < 16; ++i) {
            int idx = tid + i * 256;
            int kk = idx >> 6, cc = idx & 63;
            int r = cc >> 4, c = cc & 15;
            Ws[kk][cc] = W2[r * (DHID * NCLS) + (k0 + kk) * NCLS + c];
        }
        __syncthreads();
#pragma unroll
        for (int k = 0; k < 64; ++k) {
            float a[4], w[4];
#pragma unroll
            for (int i = 0; i < 4; ++i) a[i] = As[ty * 4 + i][k];
#pragma unroll
            for (int j = 0; j < 4; ++j) w[j] = Ws[k][tx * 4 + j];
#pragma unroll
            for (int i = 0; i < 4; ++i)
#pragma unroll
                for (int j = 0; j < 4; ++j) acc[i][j] += a[i] * w[j];
        }
        __syncthreads();
    }
#pragma unroll
    for (int i = 0; i < 4; ++i) {
        int row = row0 + ty * 4 + i;
        if (row < NNODES)
#pragma unroll
            for (int j = 0; j < 4; ++j) hw[(size_t)row * 64 + tx * 4 + j] = acc[i][j];
    }
}

__global__ void l2_out(const float* __restrict__ hw, const int* __restrict__ ofs,
                       const int* __restrict__ csr, const float* __restrict__ rs_out,
                       const float* __restrict__ rs_in, const float* __restrict__ b2,
                       float* __restrict__ out) {
    int d = blockIdx.x * 16 + (threadIdx.x >> 4);
    int c = threadIdx.x & 15;
    if (d >= NNODES) return;
    float tot = 0.f;
#pragma unroll
    for (int r = 0; r < NREL; ++r) {
        int i   = ofs[r * (NNODES + 1) + d];
        int end = ofs[r * (NNODES + 1) + d + 1];
        const int* cs = csr + (size_t)r * NEDGE;
        float acc = 0.f;
        for (; i + 2 <= end; i += 2) {
            int s0 = cs[i], s1 = cs[i + 1];
            acc += hw[(size_t)s0 * 64 + r * NCLS + c] * rs_out[r * NNODES + s0]
                 + hw[(size_t)s1 * 64 + r * NCLS + c] * rs_out[r * NNODES + s1];
        }
        for (; i < end; ++i) {
            int s = cs[i];
            acc += hw[(size_t)s * 64 + r * NCLS + c] * rs_out[r * NNODES + s];
        }
        tot += acc * rs_in[r * NNODES + d] + b2[r * NCLS + c];
    }
    out[(size_t)d * NCLS + c] = tot * 0.25f;
}

extern "C" void kernel_launch(void* const* d_in, const int* in_sizes, int n_in,
                              void* d_out, int out_size, void* d_ws, size_t ws_size,
                              hipStream_t stream) {
    const float* x  = (const float*)d_in[0];
    const float* W0 = (const float*)d_in[1];
    const float* b0 = (const float*)d_in[2];
    const float* W1 = (const float*)d_in[3];
    const float* b1 = (const float*)d_in[4];
    const float* W2 = (const float*)d_in[5];
    const float* b2 = (const float*)d_in[6];
    const int*   src = (const int*)d_in[7];
    const int*   dst = (const int*)d_in[8];
    float* out = (float*)d_out;

    // ---- workspace layout (~118 MB) ----
    char* p = (char*)d_ws;
    int* cnt_out = (int*)p;            p += sizeof(int) * NREL * NNODES;
    int* cnt_in  = (int*)p;            p += sizeof(int) * NREL * NNODES;
    int* ofs     = (int*)p;            p += sizeof(int) * NREL * (NNODES + 1) + 12; // 16B align
    int* part    = (int*)p;            p += sizeof(int) * NREL * 128;
    int* csr     = (int*)p;            p += sizeof(int) * (size_t)NREL * NEDGE;
    float* rs_out = (float*)p;         p += sizeof(float) * NREL * NNODES;
    float* rs_in  = (float*)p;         p += sizeof(float) * NREL * NNODES;
    _Float16* Wt0h = (_Float16*)p;     p += sizeof(_Float16) * NREL * DHID * DHID;
    _Float16* Wt0l = (_Float16*)p;     p += sizeof(_Float16) * NREL * DHID * DHID;
    _Float16* Wt1h = (_Float16*)p;     p += sizeof(_Float16) * NREL * DHID * DHID;
    _Float16* Wt1l = (_Float16*)p;     p += sizeof(_Float16) * NREL * DHID * DHID;
    float* h1     = (float*)p;         p += sizeof(float) * (size_t)NNODES * DHID;
    float* h2     = (float*)p;         p += sizeof(float) * (size_t)NNODES * DHID;
    float* hw     = h1;                // layer-2 reuse (h1 dead after layer-1 gconv)

    // ---- CSR + norms (once; shared by all layers; no memsets needed) ----
    dim3 hg(HR, NREL);
    hist_lds<<<hg, 512, 0, stream>>>(src, dst, cnt_out, cnt_in);
    rs_fin<<<(NREL * NNODES + 255) / 256, 256, 0, stream>>>(cnt_out, cnt_in, rs_out, rs_in);
    dim3 sg(SCANB, NREL);
    scan1<<<sg, 256, 0, stream>>>(cnt_in, part);
    scan2<<<NREL, 128, 0, stream>>>(part);
    scan3<<<sg, 256, 0, stream>>>(cnt_in, part, ofs);
    dim3 eg((NEDGE + 255) / 256, NREL);
    csr_fill<<<eg, 256, 0, stream>>>(src, dst, ofs, cnt_in, csr);

    // ---- W splits (frag layout) ----
    wsplit<<<256, 256, 0, stream>>>(W0, Wt0h, Wt0l);
    wsplit<<<256, 256, 0, stream>>>(W1, Wt1h, Wt1l);

    int gb = (NNODES + 63) / 64;

    // ---- layers 0/1: fused gather+GEMM ----
    gconv<<<gb, 512, 0, stream>>>(x,  rs_out, rs_in, ofs, csr, Wt0h, Wt0l, b0, h1);
    gconv<<<gb, 512, 0, stream>>>(h1, rs_out, rs_in, ofs, csr, Wt1h, Wt1l, b1, h2);

    // ---- layer 2: one GEMM (all relations), fused gather+epilogue ----
    gemm64<<<(NNODES + 63) / 64, 256, 0, stream>>>(h2, W2, hw);
    l2_out<<<(NNODES + 15) / 16, 256, 0, stream>>>(hw, ofs, csr, rs_out, rs_in, b2, out);
}

// Round 5
// 983.044 us; speedup vs baseline: 1.7314x; 1.7314x over previous
//
#include <hip/hip_runtime.h>

// RGCN: 3× HeteroGraphConv(mean over R=4 relations of GraphConv(norm='both')).
// R5: (a) REVERT hist_lds (510us, latency-bound 64x re-scan) -> global-atomic
// edge_hist (124us measured in R2/R3). (b) CSR carries edge weight rs_out[src]
// (int2 {s,w}) - kills the per-edge broadcast rso load chain in gconv/l2_out.
// (c) gconv gather: float2 feats, 64 thr/row -> 8 rows in flight per block
// (2x memory parallelism vs R4).

#define NNODES 100000
#define NEDGE  400000
#define NREL   4
#define DHID   128
#define NCLS   16
#define SCANB  98            // ceil(N / 1024)

typedef _Float16 f16x8 __attribute__((ext_vector_type(8)));
typedef _Float16 f16x2 __attribute__((ext_vector_type(2)));
typedef float    f32x4 __attribute__((ext_vector_type(4)));

// ---------------- degree histograms (global atomics; 124us known) ----------------
__global__ void edge_hist(const int* __restrict__ src, const int* __restrict__ dst,
                          int* __restrict__ cnt_out, int* __restrict__ cnt_in) {
    int e = blockIdx.x * 256 + threadIdx.x;
    int r = blockIdx.y;
    if (e < NEDGE) {
        atomicAdd(&cnt_out[r * NNODES + src[r * NEDGE + e]], 1);
        atomicAdd(&cnt_in [r * NNODES + dst[r * NEDGE + e]], 1);
    }
}

__global__ void rs_fin(const int* __restrict__ cnt_out, const int* __restrict__ cnt_in,
                       float* __restrict__ rs_out, float* __restrict__ rs_in) {
    int i = blockIdx.x * 256 + threadIdx.x;
    if (i < NREL * NNODES) {
        rs_out[i] = rsqrtf(fmaxf((float)cnt_out[i], 1.0f));
        rs_in [i] = rsqrtf(fmaxf((float)cnt_in [i], 1.0f));
    }
}

// ---------------- 2-level exclusive scan of cnt_in -> ofs ----------------
__global__ void scan1(const int* __restrict__ cnt, int* __restrict__ part) {
    __shared__ int sh[256];
    int r = blockIdx.y, b = blockIdx.x, tid = threadIdx.x;
    int n0 = b * 1024 + tid * 4;
    int s = 0;
#pragma unroll
    for (int j = 0; j < 4; ++j) {
        int n = n0 + j;
        s += (n < NNODES) ? cnt[r * NNODES + n] : 0;
    }
    sh[tid] = s; __syncthreads();
    for (int off = 128; off > 0; off >>= 1) {
        if (tid < off) sh[tid] += sh[tid + off];
        __syncthreads();
    }
    if (tid == 0) part[r * SCANB + b] = sh[0];
}

__global__ void scan2(int* __restrict__ part) {
    __shared__ int sh[128];
    int r = blockIdx.x, tid = threadIdx.x;
    int v = (tid < SCANB) ? part[r * SCANB + tid] : 0;
    sh[tid] = v; __syncthreads();
    for (int off = 1; off < 128; off <<= 1) {
        int t = (tid >= off) ? sh[tid - off] : 0;
        __syncthreads();
        sh[tid] += t;
        __syncthreads();
    }
    if (tid < SCANB) part[r * SCANB + tid] = sh[tid] - v;  // exclusive
}

__global__ void scan3(const int* __restrict__ cnt, const int* __restrict__ part,
                      int* __restrict__ ofs) {
    __shared__ int sh[256];
    int r = blockIdx.y, b = blockIdx.x, tid = threadIdx.x;
    int n0 = b * 1024 + tid * 4;
    int v[4];
    int tsum = 0;
#pragma unroll
    for (int j = 0; j < 4; ++j) {
        int n = n0 + j;
        v[j] = (n < NNODES) ? cnt[r * NNODES + n] : 0;
        tsum += v[j];
    }
    sh[tid] = tsum; __syncthreads();
    for (int off = 1; off < 256; off <<= 1) {
        int t = (tid >= off) ? sh[tid - off] : 0;
        __syncthreads();
        sh[tid] += t;
        __syncthreads();
    }
    int base = part[r * SCANB + b] + sh[tid] - tsum;
#pragma unroll
    for (int j = 0; j < 4; ++j) {
        int n = n0 + j;
        if (n < NNODES) ofs[r * (NNODES + 1) + n] = base;
        base += v[j];
    }
    if (b == 0 && tid == 0) ofs[r * (NNODES + 1) + NNODES] = NEDGE;
}

// fill CSR with edge weight w = rs_out[src] folded in (one producer, 3 consumers)
__global__ void csr_fill(const int* __restrict__ src, const int* __restrict__ dst,
                         const int* __restrict__ ofs, int* __restrict__ cnt_in,
                         const float* __restrict__ rs_out, int2* __restrict__ csrw) {
    int e = blockIdx.x * 256 + threadIdx.x;
    int r = blockIdx.y;
    if (e < NEDGE) {
        int s = src[r * NEDGE + e], d = dst[r * NEDGE + e];
        int k = atomicSub(&cnt_in[r * NNODES + d], 1) - 1;
        int2 ew;
        ew.x = s;
        ew.y = __float_as_int(rs_out[r * NNODES + s]);
        csrw[(size_t)r * NEDGE + ofs[r * (NNODES + 1) + d] + k] = ew;
    }
}

// ---------------- W pre-split into MFMA frag layout ----------------
// Wt[((r*16 + k>>3)*128 + c)*8 + (k&7)], value W[r][k][c] split hi/lo.
__global__ void wsplit(const float* __restrict__ W, _Float16* __restrict__ whi,
                       _Float16* __restrict__ wlo) {
    int idx = blockIdx.x * 256 + threadIdx.x;   // 4*128*128 = 65536
    int c = idx & 127, k = (idx >> 7) & 127, r = idx >> 14;
    float w = W[(size_t)r * 16384 + k * 128 + c];
    _Float16 hi = (_Float16)w;
    size_t o = (((size_t)r * 16 + (k >> 3)) * 128 + c) * 8 + (k & 7);
    whi[o] = hi;
    wlo[o] = (_Float16)(w - (float)hi);
}

// ---------------- fused GraphConv layer: gather + MFMA + epilogue ----------------
__global__ __launch_bounds__(512) void gconv(
        const float* __restrict__ H, const float* __restrict__ rs_in,
        const int* __restrict__ ofs, const int2* __restrict__ csrw,
        const _Float16* __restrict__ Wt_hi, const _Float16* __restrict__ Wt_lo,
        const float* __restrict__ bias, float* __restrict__ outH) {
    __shared__ _Float16 lhi[16 * 67 * 8];   // [kblock][row(64)+skew][8]
    __shared__ _Float16 llo[16 * 67 * 8];
    __shared__ int lofs[65];
    int tid = threadIdx.x;
    int lane = tid & 63, wid = tid >> 6;
    int wm = wid >> 2, wn = wid & 3;        // 2x4 waves: wave tile 32 rows x 32 cols
    int r15 = lane & 15;
    int row0 = blockIdx.x * 64;
    const float2* H2 = (const float2*)H;

    f32x4 oacc[2][2] = {};

    for (int r = 0; r < NREL; ++r) {
        if (tid < 65) {
            int n = row0 + tid;
            lofs[tid] = (n <= NNODES) ? ofs[r * (NNODES + 1) + n] : NEDGE;
        }
        __syncthreads();   // lofs ready; all prev-rel MFMA LDS reads done

        // --- gather: 8 rows concurrently (64 threads/row, float2 feats) ---
        {
            int j2 = tid & 63;                       // feature pair: 2*j2, 2*j2+1
            const int2*  cw  = csrw + (size_t)r * NEDGE;
            const float* rsi = rs_in + (size_t)r * NNODES;
            for (int rr = (tid >> 6); rr < 64; rr += 8) {
                int row = row0 + rr;
                float ax = 0.f, ay = 0.f;
                if (row < NNODES) {
                    int i = lofs[rr], end = lofs[rr + 1];
                    for (; i + 4 <= end; i += 4) {
                        int2 e0 = cw[i], e1 = cw[i + 1], e2 = cw[i + 2], e3 = cw[i + 3];
                        float2 v0 = H2[(size_t)e0.x * 64 + j2];
                        float2 v1 = H2[(size_t)e1.x * 64 + j2];
                        float2 v2 = H2[(size_t)e2.x * 64 + j2];
                        float2 v3 = H2[(size_t)e3.x * 64 + j2];
                        float w0 = __int_as_float(e0.y), w1 = __int_as_float(e1.y);
                        float w2 = __int_as_float(e2.y), w3 = __int_as_float(e3.y);
                        ax += v0.x * w0 + v1.x * w1 + v2.x * w2 + v3.x * w3;
                        ay += v0.y * w0 + v1.y * w1 + v2.y * w2 + v3.y * w3;
                    }
                    for (; i < end; ++i) {
                        int2 e = cw[i];
                        float2 v = H2[(size_t)e.x * 64 + j2];
                        float w = __int_as_float(e.y);
                        ax += v.x * w;
                        ay += v.y * w;
                    }
                    float rv = rsi[row];
                    ax *= rv; ay *= rv;
                }
                _Float16 hx = (_Float16)ax, hy = (_Float16)ay;
                int li = ((j2 >> 2) * 67 + rr) * 8 + ((j2 & 3) << 1);
                *(f16x2*)&lhi[li] = (f16x2){hx, hy};
                *(f16x2*)&llo[li] = (f16x2){(_Float16)(ax - (float)hx),
                                            (_Float16)(ay - (float)hy)};
            }
        }
        __syncthreads();

        // --- MFMA: K=128 in 4 kt steps ---
        f32x4 acc4[2][2] = {};
        int kb = lane >> 4;
        int rbase = wm * 32 + r15;
#pragma unroll
        for (int kt = 0; kt < 4; ++kt) {
            const _Float16* bh = Wt_hi + ((size_t)r * 16 + kt * 4 + kb) * 128 * 8;
            const _Float16* bl = Wt_lo + ((size_t)r * 16 + kt * 4 + kb) * 128 * 8;
            int c = wn * 32 + r15;
            f16x8 wh[2], wl[2], ah[2], al[2];
#pragma unroll
            for (int nf = 0; nf < 2; ++nf) {
                wh[nf] = *(const f16x8*)(bh + (size_t)(c + nf * 16) * 8);
                wl[nf] = *(const f16x8*)(bl + (size_t)(c + nf * 16) * 8);
            }
#pragma unroll
            for (int mf = 0; mf < 2; ++mf) {
                int li = ((kt * 4 + kb) * 67 + rbase + mf * 16) * 8;
                ah[mf] = *(const f16x8*)&lhi[li];
                al[mf] = *(const f16x8*)&llo[li];
            }
#pragma unroll
            for (int nf = 0; nf < 2; ++nf)
#pragma unroll
                for (int mf = 0; mf < 2; ++mf) {
                    acc4[mf][nf] = __builtin_amdgcn_mfma_f32_16x16x32_f16(ah[mf], wh[nf], acc4[mf][nf], 0, 0, 0);
                    acc4[mf][nf] = __builtin_amdgcn_mfma_f32_16x16x32_f16(ah[mf], wl[nf], acc4[mf][nf], 0, 0, 0);
                    acc4[mf][nf] = __builtin_amdgcn_mfma_f32_16x16x32_f16(al[mf], wh[nf], acc4[mf][nf], 0, 0, 0);
                }
        }

        // --- fold: oacc += relu(acc + bias_r) ---
        const float* b = bias + r * DHID;
#pragma unroll
        for (int mf = 0; mf < 2; ++mf)
#pragma unroll
            for (int nf = 0; nf < 2; ++nf) {
                float bb = b[wn * 32 + nf * 16 + r15];
#pragma unroll
                for (int i = 0; i < 4; ++i)
                    oacc[mf][nf][i] += fmaxf(acc4[mf][nf][i] + bb, 0.f);
            }
    }

    // --- epilogue: C/D layout col=lane&15, row=(lane>>4)*4+i ---
    int rsub = (lane >> 4) * 4;
#pragma unroll
    for (int mf = 0; mf < 2; ++mf)
#pragma unroll
        for (int i = 0; i < 4; ++i) {
            int row = row0 + wm * 32 + mf * 16 + rsub + i;
            if (row < NNODES) {
#pragma unroll
                for (int nf = 0; nf < 2; ++nf) {
                    int c = wn * 32 + nf * 16 + r15;
                    outH[(size_t)row * DHID + c] = oacc[mf][nf][i] * 0.25f;
                }
            }
        }
}

// ---------------- layer 2 (fp32, small): hw = H @ [W2_0|..|W2_3] ----------------
__global__ __launch_bounds__(256) void gemm64(const float* __restrict__ H,
                                              const float* __restrict__ W2,
                                              float* __restrict__ hw) {
    __shared__ float As[64][68];
    __shared__ float Ws[64][68];
    int tid = threadIdx.x;
    int tx = tid & 15, ty = tid >> 4;
    int row0 = blockIdx.x * 64;
    float acc[4][4];
#pragma unroll
    for (int i = 0; i < 4; ++i)
#pragma unroll
        for (int j = 0; j < 4; ++j) acc[i][j] = 0.f;

    for (int kt = 0; kt < 2; ++kt) {
        int k0 = kt * 64;
#pragma unroll
        for (int i = 0; i < 16; ++i) {
            int idx = tid + i * 256;
            int rr = idx >> 6, kk = idx & 63;
            int row = row0 + rr;
            As[rr][kk] = (row < NNODES) ? H[(size_t)row * DHID + k0 + kk] : 0.f;
        }
#pragma unroll
        for (int i = 0; i < 16; ++i) {
            int idx = tid + i * 256;
            int kk = idx >> 6, cc = idx & 63;
            int r = cc >> 4, c = cc & 15;
            Ws[kk][cc] = W2[r * (DHID * NCLS) + (k0 + kk) * NCLS + c];
        }
        __syncthreads();
#pragma unroll
        for (int k = 0; k < 64; ++k) {
            float a[4], w[4];
#pragma unroll
            for (int i = 0; i < 4; ++i) a[i] = As[ty * 4 + i][k];
#pragma unroll
            for (int j = 0; j < 4; ++j) w[j] = Ws[k][tx * 4 + j];
#pragma unroll
            for (int i = 0; i < 4; ++i)
#pragma unroll
                for (int j = 0; j < 4; ++j) acc[i][j] += a[i] * w[j];
        }
        __syncthreads();
    }
#pragma unroll
    for (int i = 0; i < 4; ++i) {
        int row = row0 + ty * 4 + i;
        if (row < NNODES)
#pragma unroll
            for (int j = 0; j < 4; ++j) hw[(size_t)row * 64 + tx * 4 + j] = acc[i][j];
    }
}

__global__ void l2_out(const float* __restrict__ hw, const int* __restrict__ ofs,
                       const int2* __restrict__ csrw, const float* __restrict__ rs_in,
                       const float* __restrict__ b2, float* __restrict__ out) {
    int d = blockIdx.x * 16 + (threadIdx.x >> 4);
    int c = threadIdx.x & 15;
    if (d >= NNODES) return;
    float tot = 0.f;
#pragma unroll
    for (int r = 0; r < NREL; ++r) {
        int i   = ofs[r * (NNODES + 1) + d];
        int end = ofs[r * (NNODES + 1) + d + 1];
        const int2* cw = csrw + (size_t)r * NEDGE;
        float acc = 0.f;
        for (; i + 2 <= end; i += 2) {
            int2 e0 = cw[i], e1 = cw[i + 1];
            acc += hw[(size_t)e0.x * 64 + r * NCLS + c] * __int_as_float(e0.y)
                 + hw[(size_t)e1.x * 64 + r * NCLS + c] * __int_as_float(e1.y);
        }
        for (; i < end; ++i) {
            int2 e = cw[i];
            acc += hw[(size_t)e.x * 64 + r * NCLS + c] * __int_as_float(e.y);
        }
        tot += acc * rs_in[r * NNODES + d] + b2[r * NCLS + c];
    }
    out[(size_t)d * NCLS + c] = tot * 0.25f;
}

extern "C" void kernel_launch(void* const* d_in, const int* in_sizes, int n_in,
                              void* d_out, int out_size, void* d_ws, size_t ws_size,
                              hipStream_t stream) {
    const float* x  = (const float*)d_in[0];
    const float* W0 = (const float*)d_in[1];
    const float* b0 = (const float*)d_in[2];
    const float* W1 = (const float*)d_in[3];
    const float* b1 = (const float*)d_in[4];
    const float* W2 = (const float*)d_in[5];
    const float* b2 = (const float*)d_in[6];
    const int*   src = (const int*)d_in[7];
    const int*   dst = (const int*)d_in[8];
    float* out = (float*)d_out;

    // ---- workspace layout (~125 MB); csrw first for 8B alignment ----
    char* p = (char*)d_ws;
    int2* csrw   = (int2*)p;           p += sizeof(int2) * (size_t)NREL * NEDGE;
    int* cnt_out = (int*)p;            p += sizeof(int) * NREL * NNODES;
    int* cnt_in  = (int*)p;            p += sizeof(int) * NREL * NNODES;
    int* ofs     = (int*)p;            p += sizeof(int) * NREL * (NNODES + 1) + 12; // 16B align
    int* part    = (int*)p;            p += sizeof(int) * NREL * 128;
    float* rs_out = (float*)p;         p += sizeof(float) * NREL * NNODES;
    float* rs_in  = (float*)p;         p += sizeof(float) * NREL * NNODES;
    _Float16* Wt0h = (_Float16*)p;     p += sizeof(_Float16) * NREL * DHID * DHID;
    _Float16* Wt0l = (_Float16*)p;     p += sizeof(_Float16) * NREL * DHID * DHID;
    _Float16* Wt1h = (_Float16*)p;     p += sizeof(_Float16) * NREL * DHID * DHID;
    _Float16* Wt1l = (_Float16*)p;     p += sizeof(_Float16) * NREL * DHID * DHID;
    float* h1     = (float*)p;         p += sizeof(float) * (size_t)NNODES * DHID;
    float* h2     = (float*)p;         p += sizeof(float) * (size_t)NNODES * DHID;
    float* hw     = h1;                // layer-2 reuse (h1 dead after layer-1 gconv)

    // ---- CSR + norms (once; shared by all layers) ----
    hipMemsetAsync(cnt_out, 0, 2ull * NREL * NNODES * sizeof(int), stream);
    dim3 eg((NEDGE + 255) / 256, NREL);
    edge_hist<<<eg, 256, 0, stream>>>(src, dst, cnt_out, cnt_in);
    rs_fin<<<(NREL * NNODES + 255) / 256, 256, 0, stream>>>(cnt_out, cnt_in, rs_out, rs_in);
    dim3 sg(SCANB, NREL);
    scan1<<<sg, 256, 0, stream>>>(cnt_in, part);
    scan2<<<NREL, 128, 0, stream>>>(part);
    scan3<<<sg, 256, 0, stream>>>(cnt_in, part, ofs);
    csr_fill<<<eg, 256, 0, stream>>>(src, dst, ofs, cnt_in, rs_out, csrw);

    // ---- W splits (frag layout) ----
    wsplit<<<256, 256, 0, stream>>>(W0, Wt0h, Wt0l);
    wsplit<<<256, 256, 0, stream>>>(W1, Wt1h, Wt1l);

    int gb = (NNODES + 63) / 64;

    // ---- layers 0/1: fused gather+GEMM ----
    gconv<<<gb, 512, 0, stream>>>(x,  rs_in, ofs, csrw, Wt0h, Wt0l, b0, h1);
    gconv<<<gb, 512, 0, stream>>>(h1, rs_in, ofs, csrw, Wt1h, Wt1l, b1, h2);

    // ---- layer 2: one GEMM (all relations), fused gather+epilogue ----
    gemm64<<<(NNODES + 63) / 64, 256, 0, stream>>>(h2, W2, hw);
    l2_out<<<(NNODES + 15) / 16, 256, 0, stream>>>(hw, ofs, csrw, rs_in, b2, out);
}

// Round 6
// 922.187 us; speedup vs baseline: 1.8456x; 1.0660x over previous
//
#include <hip/hip_runtime.h>

// RGCN: 3× HeteroGraphConv(mean over R=4 relations of GraphConv(norm='both')).
// R6: features stored FP16 single-plane (x pre-converted; h1/h2 written fp16 by
// gconv) -> gather row reads 512B->256B (gconv was L2-miss-traffic bound at
// 383MB/dispatch). A-side lo-plane dropped (2-term MFMA; W stays hi/lo
// compensated -> A error = storage quantization only). gemm64 -> register-frag
// MFMA from fp16 h2 (no LDS). l2_out -> 64 lanes/dst (rel-parallel + shfl_xor).

#define NNODES 100000
#define NEDGE  400000
#define NREL   4
#define DHID   128
#define NCLS   16
#define SCANB  98            // ceil(N / 1024)

typedef _Float16 f16x8 __attribute__((ext_vector_type(8)));
typedef _Float16 f16x4 __attribute__((ext_vector_type(4)));
typedef _Float16 f16x2 __attribute__((ext_vector_type(2)));
typedef float    f32x4 __attribute__((ext_vector_type(4)));

// ---------------- degree histograms (global atomics; ~124us known) ----------------
__global__ void edge_hist(const int* __restrict__ src, const int* __restrict__ dst,
                          int* __restrict__ cnt_out, int* __restrict__ cnt_in) {
    int e = blockIdx.x * 256 + threadIdx.x;
    int r = blockIdx.y;
    if (e < NEDGE) {
        atomicAdd(&cnt_out[r * NNODES + src[r * NEDGE + e]], 1);
        atomicAdd(&cnt_in [r * NNODES + dst[r * NEDGE + e]], 1);
    }
}

__global__ void rs_fin(const int* __restrict__ cnt_out, const int* __restrict__ cnt_in,
                       float* __restrict__ rs_out, float* __restrict__ rs_in) {
    int i = blockIdx.x * 256 + threadIdx.x;
    if (i < NREL * NNODES) {
        rs_out[i] = rsqrtf(fmaxf((float)cnt_out[i], 1.0f));
        rs_in [i] = rsqrtf(fmaxf((float)cnt_in [i], 1.0f));
    }
}

// ---------------- 2-level exclusive scan of cnt_in -> ofs ----------------
__global__ void scan1(const int* __restrict__ cnt, int* __restrict__ part) {
    __shared__ int sh[256];
    int r = blockIdx.y, b = blockIdx.x, tid = threadIdx.x;
    int n0 = b * 1024 + tid * 4;
    int s = 0;
#pragma unroll
    for (int j = 0; j < 4; ++j) {
        int n = n0 + j;
        s += (n < NNODES) ? cnt[r * NNODES + n] : 0;
    }
    sh[tid] = s; __syncthreads();
    for (int off = 128; off > 0; off >>= 1) {
        if (tid < off) sh[tid] += sh[tid + off];
        __syncthreads();
    }
    if (tid == 0) part[r * SCANB + b] = sh[0];
}

__global__ void scan2(int* __restrict__ part) {
    __shared__ int sh[128];
    int r = blockIdx.x, tid = threadIdx.x;
    int v = (tid < SCANB) ? part[r * SCANB + tid] : 0;
    sh[tid] = v; __syncthreads();
    for (int off = 1; off < 128; off <<= 1) {
        int t = (tid >= off) ? sh[tid - off] : 0;
        __syncthreads();
        sh[tid] += t;
        __syncthreads();
    }
    if (tid < SCANB) part[r * SCANB + tid] = sh[tid] - v;  // exclusive
}

__global__ void scan3(const int* __restrict__ cnt, const int* __restrict__ part,
                      int* __restrict__ ofs) {
    __shared__ int sh[256];
    int r = blockIdx.y, b = blockIdx.x, tid = threadIdx.x;
    int n0 = b * 1024 + tid * 4;
    int v[4];
    int tsum = 0;
#pragma unroll
    for (int j = 0; j < 4; ++j) {
        int n = n0 + j;
        v[j] = (n < NNODES) ? cnt[r * NNODES + n] : 0;
        tsum += v[j];
    }
    sh[tid] = tsum; __syncthreads();
    for (int off = 1; off < 256; off <<= 1) {
        int t = (tid >= off) ? sh[tid - off] : 0;
        __syncthreads();
        sh[tid] += t;
        __syncthreads();
    }
    int base = part[r * SCANB + b] + sh[tid] - tsum;
#pragma unroll
    for (int j = 0; j < 4; ++j) {
        int n = n0 + j;
        if (n < NNODES) ofs[r * (NNODES + 1) + n] = base;
        base += v[j];
    }
    if (b == 0 && tid == 0) ofs[r * (NNODES + 1) + NNODES] = NEDGE;
}

// fill CSR with edge weight w = rs_out[src] folded in
__global__ void csr_fill(const int* __restrict__ src, const int* __restrict__ dst,
                         const int* __restrict__ ofs, int* __restrict__ cnt_in,
                         const float* __restrict__ rs_out, int2* __restrict__ csrw) {
    int e = blockIdx.x * 256 + threadIdx.x;
    int r = blockIdx.y;
    if (e < NEDGE) {
        int s = src[r * NEDGE + e], d = dst[r * NEDGE + e];
        int k = atomicSub(&cnt_in[r * NNODES + d], 1) - 1;
        int2 ew;
        ew.x = s;
        ew.y = __float_as_int(rs_out[r * NNODES + s]);
        csrw[(size_t)r * NEDGE + ofs[r * (NNODES + 1) + d] + k] = ew;
    }
}

// ---------------- W pre-split into MFMA frag layout ----------------
// Wt[((r*16 + k>>3)*128 + c)*8 + (k&7)], value W[r][k][c] split hi/lo.
__global__ void wsplit(const float* __restrict__ W, _Float16* __restrict__ whi,
                       _Float16* __restrict__ wlo) {
    int idx = blockIdx.x * 256 + threadIdx.x;   // 4*128*128 = 65536
    int c = idx & 127, k = (idx >> 7) & 127, r = idx >> 14;
    float w = W[(size_t)r * 16384 + k * 128 + c];
    _Float16 hi = (_Float16)w;
    size_t o = (((size_t)r * 16 + (k >> 3)) * 128 + c) * 8 + (k & 7);
    whi[o] = hi;
    wlo[o] = (_Float16)(w - (float)hi);
}

// W2 [4][128][16] -> frag layout [k>>3][r*16+c][k&7], hi/lo
__global__ void wsplit2(const float* __restrict__ W2, _Float16* __restrict__ wh,
                        _Float16* __restrict__ wl) {
    int idx = blockIdx.x * 256 + threadIdx.x;   // 8192
    if (idx < NREL * DHID * NCLS) {
        int c = idx & 15, k = (idx >> 4) & 127, r = idx >> 11;
        float w = W2[idx];
        _Float16 hi = (_Float16)w;
        size_t o = ((size_t)(k >> 3) * 64 + r * 16 + c) * 8 + (k & 7);
        wh[o] = hi;
        wl[o] = (_Float16)(w - (float)hi);
    }
}

// ---------------- x -> fp16 plane ----------------
__global__ void xcvt(const float* __restrict__ x, _Float16* __restrict__ xh) {
    int i = blockIdx.x * 256 + threadIdx.x;     // over N*DHID/4
    if (i < NNODES * DHID / 4) {
        float4 v = ((const float4*)x)[i];
        f16x4 h = {(_Float16)v.x, (_Float16)v.y, (_Float16)v.z, (_Float16)v.w};
        *(f16x4*)&xh[(size_t)i * 4] = h;
    }
}

// ---------------- fused GraphConv layer: gather(fp16) + MFMA + epilogue ----------------
__global__ __launch_bounds__(512) void gconv(
        const _Float16* __restrict__ Hh, const float* __restrict__ rs_in,
        const int* __restrict__ ofs, const int2* __restrict__ csrw,
        const _Float16* __restrict__ Wt_hi, const _Float16* __restrict__ Wt_lo,
        const float* __restrict__ bias, _Float16* __restrict__ outH) {
    __shared__ _Float16 lhi[16 * 67 * 8];   // [kblock][row(64)+skew][8]  17.2KB
    __shared__ int lofs[65];
    int tid = threadIdx.x;
    int lane = tid & 63, wid = tid >> 6;
    int wm = wid >> 2, wn = wid & 3;        // 2x4 waves: wave tile 32 rows x 32 cols
    int r15 = lane & 15;
    int row0 = blockIdx.x * 64;
    const f16x2* H2 = (const f16x2*)Hh;     // row stride 64 pairs

    f32x4 oacc[2][2] = {};

    for (int r = 0; r < NREL; ++r) {
        if (tid < 65) {
            int n = row0 + tid;
            lofs[tid] = (n <= NNODES) ? ofs[r * (NNODES + 1) + n] : NEDGE;
        }
        __syncthreads();   // lofs ready; all prev-rel MFMA LDS reads done

        // --- gather: 8 rows in flight (64 threads/row, f16x2 feats) ---
        {
            int j2 = tid & 63;                       // feature pair 2*j2, 2*j2+1
            const int2*  cw  = csrw + (size_t)r * NEDGE;
            const float* rsi = rs_in + (size_t)r * NNODES;
            for (int rr = (tid >> 6); rr < 64; rr += 8) {
                int row = row0 + rr;
                float ax = 0.f, ay = 0.f;
                if (row < NNODES) {
                    int i = lofs[rr], end = lofs[rr + 1];
                    for (; i + 4 <= end; i += 4) {
                        int2 e0 = cw[i], e1 = cw[i + 1], e2 = cw[i + 2], e3 = cw[i + 3];
                        f16x2 v0 = H2[(size_t)e0.x * 64 + j2];
                        f16x2 v1 = H2[(size_t)e1.x * 64 + j2];
                        f16x2 v2 = H2[(size_t)e2.x * 64 + j2];
                        f16x2 v3 = H2[(size_t)e3.x * 64 + j2];
                        float w0 = __int_as_float(e0.y), w1 = __int_as_float(e1.y);
                        float w2 = __int_as_float(e2.y), w3 = __int_as_float(e3.y);
                        ax += (float)v0[0] * w0 + (float)v1[0] * w1
                            + (float)v2[0] * w2 + (float)v3[0] * w3;
                        ay += (float)v0[1] * w0 + (float)v1[1] * w1
                            + (float)v2[1] * w2 + (float)v3[1] * w3;
                    }
                    for (; i < end; ++i) {
                        int2 e = cw[i];
                        f16x2 v = H2[(size_t)e.x * 64 + j2];
                        float w = __int_as_float(e.y);
                        ax += (float)v[0] * w;
                        ay += (float)v[1] * w;
                    }
                    float rv = rsi[row];
                    ax *= rv; ay *= rv;
                }
                int li = ((j2 >> 2) * 67 + rr) * 8 + ((j2 & 3) << 1);
                *(f16x2*)&lhi[li] = (f16x2){(_Float16)ax, (_Float16)ay};
            }
        }
        __syncthreads();

        // --- MFMA: K=128 in 4 kt steps, 2-term (A single plane, W compensated) ---
        f32x4 acc4[2][2] = {};
        int kb = lane >> 4;
        int rbase = wm * 32 + r15;
#pragma unroll
        for (int kt = 0; kt < 4; ++kt) {
            const _Float16* bh = Wt_hi + ((size_t)r * 16 + kt * 4 + kb) * 128 * 8;
            const _Float16* bl = Wt_lo + ((size_t)r * 16 + kt * 4 + kb) * 128 * 8;
            int c = wn * 32 + r15;
            f16x8 wh[2], wl[2], ah[2];
#pragma unroll
            for (int nf = 0; nf < 2; ++nf) {
                wh[nf] = *(const f16x8*)(bh + (size_t)(c + nf * 16) * 8);
                wl[nf] = *(const f16x8*)(bl + (size_t)(c + nf * 16) * 8);
            }
#pragma unroll
            for (int mf = 0; mf < 2; ++mf) {
                int li = ((kt * 4 + kb) * 67 + rbase + mf * 16) * 8;
                ah[mf] = *(const f16x8*)&lhi[li];
            }
#pragma unroll
            for (int nf = 0; nf < 2; ++nf)
#pragma unroll
                for (int mf = 0; mf < 2; ++mf) {
                    acc4[mf][nf] = __builtin_amdgcn_mfma_f32_16x16x32_f16(ah[mf], wh[nf], acc4[mf][nf], 0, 0, 0);
                    acc4[mf][nf] = __builtin_amdgcn_mfma_f32_16x16x32_f16(ah[mf], wl[nf], acc4[mf][nf], 0, 0, 0);
                }
        }

        // --- fold: oacc += relu(acc + bias_r) ---
        const float* b = bias + r * DHID;
#pragma unroll
        for (int mf = 0; mf < 2; ++mf)
#pragma unroll
            for (int nf = 0; nf < 2; ++nf) {
                float bb = b[wn * 32 + nf * 16 + r15];
#pragma unroll
                for (int i = 0; i < 4; ++i)
                    oacc[mf][nf][i] += fmaxf(acc4[mf][nf][i] + bb, 0.f);
            }
    }

    // --- epilogue: C/D layout col=lane&15, row=(lane>>4)*4+i; write fp16 h ---
    int rsub = (lane >> 4) * 4;
#pragma unroll
    for (int mf = 0; mf < 2; ++mf)
#pragma unroll
        for (int i = 0; i < 4; ++i) {
            int row = row0 + wm * 32 + mf * 16 + rsub + i;
            if (row < NNODES) {
#pragma unroll
                for (int nf = 0; nf < 2; ++nf) {
                    int c = wn * 32 + nf * 16 + r15;
                    outH[(size_t)row * DHID + c] = (_Float16)(oacc[mf][nf][i] * 0.25f);
                }
            }
        }
}

// ---------------- layer 2 GEMM: hw = h2(fp16) @ [W2_0|..|W2_3], reg-frag MFMA ----------------
__global__ __launch_bounds__(256) void gemm64h(const _Float16* __restrict__ Hh,
                                               const _Float16* __restrict__ W2h,
                                               const _Float16* __restrict__ W2l,
                                               float* __restrict__ hw) {
    int tid = threadIdx.x, lane = tid & 63, wid = tid >> 6;
    int row0 = blockIdx.x * 64;
    int arow = row0 + wid * 16 + (lane & 15);
    int kb = lane >> 4;
    f32x4 acc[4] = {};
#pragma unroll
    for (int kt = 0; kt < 4; ++kt) {
        f16x8 a = {};
        if (arow < NNODES)
            a = *(const f16x8*)&Hh[(size_t)arow * DHID + kt * 32 + kb * 8];
        const _Float16* bh = W2h + ((size_t)(kt * 4 + kb) * 64) * 8;
        const _Float16* bl = W2l + ((size_t)(kt * 4 + kb) * 64) * 8;
#pragma unroll
        for (int nf = 0; nf < 4; ++nf) {
            f16x8 wh = *(const f16x8*)(bh + (size_t)(nf * 16 + (lane & 15)) * 8);
            f16x8 wl = *(const f16x8*)(bl + (size_t)(nf * 16 + (lane & 15)) * 8);
            acc[nf] = __builtin_amdgcn_mfma_f32_16x16x32_f16(a, wh, acc[nf], 0, 0, 0);
            acc[nf] = __builtin_amdgcn_mfma_f32_16x16x32_f16(a, wl, acc[nf], 0, 0, 0);
        }
    }
    int rsub = (lane >> 4) * 4;
#pragma unroll
    for (int nf = 0; nf < 4; ++nf)
#pragma unroll
        for (int i = 0; i < 4; ++i) {
            int row = row0 + wid * 16 + rsub + i;
            if (row < NNODES) hw[(size_t)row * 64 + nf * 16 + (lane & 15)] = acc[nf][i];
        }
}

// ---------------- layer-2 gather+epilogue: 64 lanes/dst (16 per rel), shfl reduce ----------------
__global__ __launch_bounds__(256) void l2_out(const float* __restrict__ hw,
                                              const int* __restrict__ ofs,
                                              const int2* __restrict__ csrw,
                                              const float* __restrict__ rs_in,
                                              const float* __restrict__ b2,
                                              float* __restrict__ out) {
    int t = threadIdx.x;
    int d = blockIdx.x * 4 + (t >> 6);
    int lane = t & 63;
    int r = lane >> 4;          // relation
    int c = lane & 15;          // class
    if (d >= NNODES) return;
    int i   = ofs[r * (NNODES + 1) + d];
    int end = ofs[r * (NNODES + 1) + d + 1];
    const int2* cw = csrw + (size_t)r * NEDGE;
    float acc = 0.f;
    for (; i + 2 <= end; i += 2) {
        int2 e0 = cw[i], e1 = cw[i + 1];
        acc += hw[(size_t)e0.x * 64 + r * NCLS + c] * __int_as_float(e0.y)
             + hw[(size_t)e1.x * 64 + r * NCLS + c] * __int_as_float(e1.y);
    }
    for (; i < end; ++i) {
        int2 e = cw[i];
        acc += hw[(size_t)e.x * 64 + r * NCLS + c] * __int_as_float(e.y);
    }
    float tot = acc * rs_in[r * NNODES + d] + b2[r * NCLS + c];
    tot += __shfl_xor(tot, 16, 64);
    tot += __shfl_xor(tot, 32, 64);
    if (r == 0) out[(size_t)d * NCLS + c] = tot * 0.25f;
}

extern "C" void kernel_launch(void* const* d_in, const int* in_sizes, int n_in,
                              void* d_out, int out_size, void* d_ws, size_t ws_size,
                              hipStream_t stream) {
    const float* x  = (const float*)d_in[0];
    const float* W0 = (const float*)d_in[1];
    const float* b0 = (const float*)d_in[2];
    const float* W1 = (const float*)d_in[3];
    const float* b1 = (const float*)d_in[4];
    const float* W2 = (const float*)d_in[5];
    const float* b2 = (const float*)d_in[6];
    const int*   src = (const int*)d_in[7];
    const int*   dst = (const int*)d_in[8];
    float* out = (float*)d_out;

    // ---- workspace layout (~122 MB); 8B-aligned blocks first ----
    char* p = (char*)d_ws;
    int2* csrw   = (int2*)p;           p += sizeof(int2) * (size_t)NREL * NEDGE;
    float* hw    = (float*)p;          p += sizeof(float) * (size_t)NNODES * 64;
    int* cnt_out = (int*)p;            p += sizeof(int) * NREL * NNODES;
    int* cnt_in  = (int*)p;            p += sizeof(int) * NREL * NNODES;
    int* ofs     = (int*)p;            p += sizeof(int) * NREL * (NNODES + 1) + 12; // 16B align
    int* part    = (int*)p;            p += sizeof(int) * NREL * 128;
    float* rs_out = (float*)p;         p += sizeof(float) * NREL * NNODES;
    float* rs_in  = (float*)p;         p += sizeof(float) * NREL * NNODES;
    _Float16* Wt0h = (_Float16*)p;     p += sizeof(_Float16) * NREL * DHID * DHID;
    _Float16* Wt0l = (_Float16*)p;     p += sizeof(_Float16) * NREL * DHID * DHID;
    _Float16* Wt1h = (_Float16*)p;     p += sizeof(_Float16) * NREL * DHID * DHID;
    _Float16* Wt1l = (_Float16*)p;     p += sizeof(_Float16) * NREL * DHID * DHID;
    _Float16* W2h  = (_Float16*)p;     p += sizeof(_Float16) * 16 * 64 * 8;
    _Float16* W2l  = (_Float16*)p;     p += sizeof(_Float16) * 16 * 64 * 8;
    _Float16* xh   = (_Float16*)p;     p += sizeof(_Float16) * (size_t)NNODES * DHID;
    _Float16* h1   = (_Float16*)p;     p += sizeof(_Float16) * (size_t)NNODES * DHID;
    _Float16* h2   = (_Float16*)p;     p += sizeof(_Float16) * (size_t)NNODES * DHID;

    // ---- CSR + norms (once; shared by all layers) ----
    hipMemsetAsync(cnt_out, 0, 2ull * NREL * NNODES * sizeof(int), stream);
    dim3 eg((NEDGE + 255) / 256, NREL);
    edge_hist<<<eg, 256, 0, stream>>>(src, dst, cnt_out, cnt_in);
    rs_fin<<<(NREL * NNODES + 255) / 256, 256, 0, stream>>>(cnt_out, cnt_in, rs_out, rs_in);
    dim3 sg(SCANB, NREL);
    scan1<<<sg, 256, 0, stream>>>(cnt_in, part);
    scan2<<<NREL, 128, 0, stream>>>(part);
    scan3<<<sg, 256, 0, stream>>>(cnt_in, part, ofs);
    csr_fill<<<eg, 256, 0, stream>>>(src, dst, ofs, cnt_in, rs_out, csrw);

    // ---- weight splits + x conversion ----
    wsplit<<<256, 256, 0, stream>>>(W0, Wt0h, Wt0l);
    wsplit<<<256, 256, 0, stream>>>(W1, Wt1h, Wt1l);
    wsplit2<<<32, 256, 0, stream>>>(W2, W2h, W2l);
    xcvt<<<(NNODES * DHID / 4 + 255) / 256, 256, 0, stream>>>(x, xh);

    int gb = (NNODES + 63) / 64;

    // ---- layers 0/1: fused gather+GEMM (fp16 features) ----
    gconv<<<gb, 512, 0, stream>>>(xh, rs_in, ofs, csrw, Wt0h, Wt0l, b0, h1);
    gconv<<<gb, 512, 0, stream>>>(h1, rs_in, ofs, csrw, Wt1h, Wt1l, b1, h2);

    // ---- layer 2: one MFMA GEMM (all relations), gather+epilogue ----
    gemm64h<<<gb, 256, 0, stream>>>(h2, W2h, W2l, hw);
    l2_out<<<(NNODES + 3) / 4, 256, 0, stream>>>(hw, ofs, csrw, rs_in, b2, out);
}

// Round 7
// 686.878 us; speedup vs baseline: 2.4779x; 1.3426x over previous
//
#include <hip/hip_runtime.h>

// RGCN: 3× HeteroGraphConv(mean over R=4 relations of GraphConv(norm='both')).
// R7: gconv gather restructured for MLP (R6 showed it's load-issue bound, not
// bytes-bound: halving bytes only -10%): 16 lanes/row ds f16x8 16B loads (4x
// fewer loads, 4x bytes in flight, coalesced 256B row per 16-lane group; LDS
// write = one b128 into the MFMA frag slot). Single-pass: all 4 rels staged
// in LDS (68.6KB, 2 blk/CU), 2 barriers total, 32 row-gathers in flight/block.

#define NNODES 100000
#define NEDGE  400000
#define NREL   4
#define DHID   128
#define NCLS   16
#define SCANB  98            // ceil(N / 1024)

typedef _Float16 f16x8 __attribute__((ext_vector_type(8)));
typedef _Float16 f16x4 __attribute__((ext_vector_type(4)));
typedef float    f32x4 __attribute__((ext_vector_type(4)));

// ---------------- degree histograms (global atomics; ~124us known) ----------------
__global__ void edge_hist(const int* __restrict__ src, const int* __restrict__ dst,
                          int* __restrict__ cnt_out, int* __restrict__ cnt_in) {
    int e = blockIdx.x * 256 + threadIdx.x;
    int r = blockIdx.y;
    if (e < NEDGE) {
        atomicAdd(&cnt_out[r * NNODES + src[r * NEDGE + e]], 1);
        atomicAdd(&cnt_in [r * NNODES + dst[r * NEDGE + e]], 1);
    }
}

__global__ void rs_fin(const int* __restrict__ cnt_out, const int* __restrict__ cnt_in,
                       float* __restrict__ rs_out, float* __restrict__ rs_in) {
    int i = blockIdx.x * 256 + threadIdx.x;
    if (i < NREL * NNODES) {
        rs_out[i] = rsqrtf(fmaxf((float)cnt_out[i], 1.0f));
        rs_in [i] = rsqrtf(fmaxf((float)cnt_in [i], 1.0f));
    }
}

// ---------------- 2-level exclusive scan of cnt_in -> ofs ----------------
__global__ void scan1(const int* __restrict__ cnt, int* __restrict__ part) {
    __shared__ int sh[256];
    int r = blockIdx.y, b = blockIdx.x, tid = threadIdx.x;
    int n0 = b * 1024 + tid * 4;
    int s = 0;
#pragma unroll
    for (int j = 0; j < 4; ++j) {
        int n = n0 + j;
        s += (n < NNODES) ? cnt[r * NNODES + n] : 0;
    }
    sh[tid] = s; __syncthreads();
    for (int off = 128; off > 0; off >>= 1) {
        if (tid < off) sh[tid] += sh[tid + off];
        __syncthreads();
    }
    if (tid == 0) part[r * SCANB + b] = sh[0];
}

__global__ void scan2(int* __restrict__ part) {
    __shared__ int sh[128];
    int r = blockIdx.x, tid = threadIdx.x;
    int v = (tid < SCANB) ? part[r * SCANB + tid] : 0;
    sh[tid] = v; __syncthreads();
    for (int off = 1; off < 128; off <<= 1) {
        int t = (tid >= off) ? sh[tid - off] : 0;
        __syncthreads();
        sh[tid] += t;
        __syncthreads();
    }
    if (tid < SCANB) part[r * SCANB + tid] = sh[tid] - v;  // exclusive
}

__global__ void scan3(const int* __restrict__ cnt, const int* __restrict__ part,
                      int* __restrict__ ofs) {
    __shared__ int sh[256];
    int r = blockIdx.y, b = blockIdx.x, tid = threadIdx.x;
    int n0 = b * 1024 + tid * 4;
    int v[4];
    int tsum = 0;
#pragma unroll
    for (int j = 0; j < 4; ++j) {
        int n = n0 + j;
        v[j] = (n < NNODES) ? cnt[r * NNODES + n] : 0;
        tsum += v[j];
    }
    sh[tid] = tsum; __syncthreads();
    for (int off = 1; off < 256; off <<= 1) {
        int t = (tid >= off) ? sh[tid - off] : 0;
        __syncthreads();
        sh[tid] += t;
        __syncthreads();
    }
    int base = part[r * SCANB + b] + sh[tid] - tsum;
#pragma unroll
    for (int j = 0; j < 4; ++j) {
        int n = n0 + j;
        if (n < NNODES) ofs[r * (NNODES + 1) + n] = base;
        base += v[j];
    }
    if (b == 0 && tid == 0) ofs[r * (NNODES + 1) + NNODES] = NEDGE;
}

// fill CSR with edge weight w = rs_out[src] folded in
__global__ void csr_fill(const int* __restrict__ src, const int* __restrict__ dst,
                         const int* __restrict__ ofs, int* __restrict__ cnt_in,
                         const float* __restrict__ rs_out, int2* __restrict__ csrw) {
    int e = blockIdx.x * 256 + threadIdx.x;
    int r = blockIdx.y;
    if (e < NEDGE) {
        int s = src[r * NEDGE + e], d = dst[r * NEDGE + e];
        int k = atomicSub(&cnt_in[r * NNODES + d], 1) - 1;
        int2 ew;
        ew.x = s;
        ew.y = __float_as_int(rs_out[r * NNODES + s]);
        csrw[(size_t)r * NEDGE + ofs[r * (NNODES + 1) + d] + k] = ew;
    }
}

// ---------------- W pre-split into MFMA frag layout ----------------
// Wt[((r*16 + k>>3)*128 + c)*8 + (k&7)], value W[r][k][c] split hi/lo.
__global__ void wsplit(const float* __restrict__ W, _Float16* __restrict__ whi,
                       _Float16* __restrict__ wlo) {
    int idx = blockIdx.x * 256 + threadIdx.x;   // 4*128*128 = 65536
    int c = idx & 127, k = (idx >> 7) & 127, r = idx >> 14;
    float w = W[(size_t)r * 16384 + k * 128 + c];
    _Float16 hi = (_Float16)w;
    size_t o = (((size_t)r * 16 + (k >> 3)) * 128 + c) * 8 + (k & 7);
    whi[o] = hi;
    wlo[o] = (_Float16)(w - (float)hi);
}

// W2 [4][128][16] -> frag layout [k>>3][r*16+c][k&7], hi/lo
__global__ void wsplit2(const float* __restrict__ W2, _Float16* __restrict__ wh,
                        _Float16* __restrict__ wl) {
    int idx = blockIdx.x * 256 + threadIdx.x;   // 8192
    if (idx < NREL * DHID * NCLS) {
        int c = idx & 15, k = (idx >> 4) & 127, r = idx >> 11;
        float w = W2[idx];
        _Float16 hi = (_Float16)w;
        size_t o = ((size_t)(k >> 3) * 64 + r * 16 + c) * 8 + (k & 7);
        wh[o] = hi;
        wl[o] = (_Float16)(w - (float)hi);
    }
}

// ---------------- x -> fp16 plane ----------------
__global__ void xcvt(const float* __restrict__ x, _Float16* __restrict__ xh) {
    int i = blockIdx.x * 256 + threadIdx.x;     // over N*DHID/4
    if (i < NNODES * DHID / 4) {
        float4 v = ((const float4*)x)[i];
        f16x4 h = {(_Float16)v.x, (_Float16)v.y, (_Float16)v.z, (_Float16)v.w};
        *(f16x4*)&xh[(size_t)i * 4] = h;
    }
}

// ---------------- fused GraphConv layer: gather(16B loads) + MFMA + epilogue ----------------
__global__ __launch_bounds__(512) void gconv(
        const _Float16* __restrict__ Hh, const float* __restrict__ rs_in,
        const int* __restrict__ ofs, const int2* __restrict__ csrw,
        const _Float16* __restrict__ Wt_hi, const _Float16* __restrict__ Wt_lo,
        const float* __restrict__ bias, _Float16* __restrict__ outH) {
    __shared__ _Float16 lhi[4 * 16 * 67 * 8];   // [rel][kblk][row+skew][8]  68.6KB
    __shared__ int lofs[NREL][65];
    int tid = threadIdx.x;
    int lane = tid & 63, wid = tid >> 6;
    int wm = wid >> 2, wn = wid & 3;        // 2x4 waves: wave tile 32 rows x 32 cols
    int r15 = lane & 15;
    int row0 = blockIdx.x * 64;

    if (tid < 4 * 65) {
        int rel = tid / 65, i = tid - rel * 65;
        int n = row0 + i;
        lofs[rel][i] = (n <= NNODES) ? ofs[rel * (NNODES + 1) + n] : NEDGE;
    }
    __syncthreads();

    // ---- gather ALL 4 relations: 16 lanes/row, f16x8 (16B) loads ----
    {
        int lane16 = tid & 15;          // feature block: feats lane16*8 .. +7
        int grp    = tid >> 4;          // 0..31 -> 32 (row,rel) gathers in flight
        const _Float16* hb = Hh + (size_t)lane16 * 8;
        for (int idx = grp; idx < 256; idx += 32) {
            int rel = idx >> 6, rr = idx & 63;
            int row = row0 + rr;
            float acc[8] = {};
            if (row < NNODES) {
                int i = lofs[rel][rr], end = lofs[rel][rr + 1];
                const int2* cw = csrw + (size_t)rel * NEDGE;
                for (; i + 4 <= end; i += 4) {      // 4 x 16B in flight
                    int2 e0 = cw[i], e1 = cw[i + 1], e2 = cw[i + 2], e3 = cw[i + 3];
                    f16x8 v0 = *(const f16x8*)(hb + (size_t)e0.x * DHID);
                    f16x8 v1 = *(const f16x8*)(hb + (size_t)e1.x * DHID);
                    f16x8 v2 = *(const f16x8*)(hb + (size_t)e2.x * DHID);
                    f16x8 v3 = *(const f16x8*)(hb + (size_t)e3.x * DHID);
                    float w0 = __int_as_float(e0.y), w1 = __int_as_float(e1.y);
                    float w2 = __int_as_float(e2.y), w3 = __int_as_float(e3.y);
#pragma unroll
                    for (int j = 0; j < 8; ++j)
                        acc[j] += ((float)v0[j] * w0 + (float)v1[j] * w1)
                                + ((float)v2[j] * w2 + (float)v3[j] * w3);
                }
                for (; i < end; ++i) {
                    int2 e = cw[i];
                    f16x8 v = *(const f16x8*)(hb + (size_t)e.x * DHID);
                    float w = __int_as_float(e.y);
#pragma unroll
                    for (int j = 0; j < 8; ++j) acc[j] += (float)v[j] * w;
                }
                float rv = rs_in[rel * NNODES + row];
#pragma unroll
                for (int j = 0; j < 8; ++j) acc[j] *= rv;
            }
            f16x8 o;
#pragma unroll
            for (int j = 0; j < 8; ++j) o[j] = (_Float16)acc[j];
            *(f16x8*)&lhi[(((rel * 16 + lane16) * 67) + rr) * 8] = o;   // one b128
        }
    }
    __syncthreads();

    // ---- MFMA: 4 relations back-to-back, K=128 each, 2-term (W hi/lo) ----
    f32x4 oacc[2][2] = {};
    int kb = lane >> 4;
    int rbase = wm * 32 + r15;
    int c = wn * 32 + r15;
    for (int rel = 0; rel < NREL; ++rel) {
        f32x4 acc4[2][2] = {};
#pragma unroll
        for (int kt = 0; kt < 4; ++kt) {
            const _Float16* bh = Wt_hi + ((size_t)rel * 16 + kt * 4 + kb) * 128 * 8;
            const _Float16* bl = Wt_lo + ((size_t)rel * 16 + kt * 4 + kb) * 128 * 8;
            f16x8 wh[2], wl[2], ah[2];
#pragma unroll
            for (int nf = 0; nf < 2; ++nf) {
                wh[nf] = *(const f16x8*)(bh + (size_t)(c + nf * 16) * 8);
                wl[nf] = *(const f16x8*)(bl + (size_t)(c + nf * 16) * 8);
            }
#pragma unroll
            for (int mf = 0; mf < 2; ++mf) {
                int li = (((rel * 16 + kt * 4 + kb) * 67) + rbase + mf * 16) * 8;
                ah[mf] = *(const f16x8*)&lhi[li];
            }
#pragma unroll
            for (int nf = 0; nf < 2; ++nf)
#pragma unroll
                for (int mf = 0; mf < 2; ++mf) {
                    acc4[mf][nf] = __builtin_amdgcn_mfma_f32_16x16x32_f16(ah[mf], wh[nf], acc4[mf][nf], 0, 0, 0);
                    acc4[mf][nf] = __builtin_amdgcn_mfma_f32_16x16x32_f16(ah[mf], wl[nf], acc4[mf][nf], 0, 0, 0);
                }
        }
        const float* b = bias + rel * DHID;
#pragma unroll
        for (int mf = 0; mf < 2; ++mf)
#pragma unroll
            for (int nf = 0; nf < 2; ++nf) {
                float bb = b[wn * 32 + nf * 16 + r15];
#pragma unroll
                for (int i = 0; i < 4; ++i)
                    oacc[mf][nf][i] += fmaxf(acc4[mf][nf][i] + bb, 0.f);
            }
    }

    // ---- epilogue: C/D layout col=lane&15, row=(lane>>4)*4+i; write fp16 h ----
    int rsub = (lane >> 4) * 4;
#pragma unroll
    for (int mf = 0; mf < 2; ++mf)
#pragma unroll
        for (int i = 0; i < 4; ++i) {
            int row = row0 + wm * 32 + mf * 16 + rsub + i;
            if (row < NNODES) {
#pragma unroll
                for (int nf = 0; nf < 2; ++nf) {
                    int cc = wn * 32 + nf * 16 + r15;
                    outH[(size_t)row * DHID + cc] = (_Float16)(oacc[mf][nf][i] * 0.25f);
                }
            }
        }
}

// ---------------- layer 2 GEMM: hw = h2(fp16) @ [W2_0|..|W2_3], reg-frag MFMA ----------------
__global__ __launch_bounds__(256) void gemm64h(const _Float16* __restrict__ Hh,
                                               const _Float16* __restrict__ W2h,
                                               const _Float16* __restrict__ W2l,
                                               float* __restrict__ hw) {
    int tid = threadIdx.x, lane = tid & 63, wid = tid >> 6;
    int row0 = blockIdx.x * 64;
    int arow = row0 + wid * 16 + (lane & 15);
    int kb = lane >> 4;
    f32x4 acc[4] = {};
#pragma unroll
    for (int kt = 0; kt < 4; ++kt) {
        f16x8 a = {};
        if (arow < NNODES)
            a = *(const f16x8*)&Hh[(size_t)arow * DHID + kt * 32 + kb * 8];
        const _Float16* bh = W2h + ((size_t)(kt * 4 + kb) * 64) * 8;
        const _Float16* bl = W2l + ((size_t)(kt * 4 + kb) * 64) * 8;
#pragma unroll
        for (int nf = 0; nf < 4; ++nf) {
            f16x8 wh = *(const f16x8*)(bh + (size_t)(nf * 16 + (lane & 15)) * 8);
            f16x8 wl = *(const f16x8*)(bl + (size_t)(nf * 16 + (lane & 15)) * 8);
            acc[nf] = __builtin_amdgcn_mfma_f32_16x16x32_f16(a, wh, acc[nf], 0, 0, 0);
            acc[nf] = __builtin_amdgcn_mfma_f32_16x16x32_f16(a, wl, acc[nf], 0, 0, 0);
        }
    }
    int rsub = (lane >> 4) * 4;
#pragma unroll
    for (int nf = 0; nf < 4; ++nf)
#pragma unroll
        for (int i = 0; i < 4; ++i) {
            int row = row0 + wid * 16 + rsub + i;
            if (row < NNODES) hw[(size_t)row * 64 + nf * 16 + (lane & 15)] = acc[nf][i];
        }
}

// ---------------- layer-2 gather+epilogue: 64 lanes/dst (16 per rel), shfl reduce ----------------
__global__ __launch_bounds__(256) void l2_out(const float* __restrict__ hw,
                                              const int* __restrict__ ofs,
                                              const int2* __restrict__ csrw,
                                              const float* __restrict__ rs_in,
                                              const float* __restrict__ b2,
                                              float* __restrict__ out) {
    int t = threadIdx.x;
    int d = blockIdx.x * 4 + (t >> 6);
    int lane = t & 63;
    int r = lane >> 4;          // relation
    int c = lane & 15;          // class
    if (d >= NNODES) return;
    int i   = ofs[r * (NNODES + 1) + d];
    int end = ofs[r * (NNODES + 1) + d + 1];
    const int2* cw = csrw + (size_t)r * NEDGE;
    float acc = 0.f;
    for (; i + 2 <= end; i += 2) {
        int2 e0 = cw[i], e1 = cw[i + 1];
        acc += hw[(size_t)e0.x * 64 + r * NCLS + c] * __int_as_float(e0.y)
             + hw[(size_t)e1.x * 64 + r * NCLS + c] * __int_as_float(e1.y);
    }
    for (; i < end; ++i) {
        int2 e = cw[i];
        acc += hw[(size_t)e.x * 64 + r * NCLS + c] * __int_as_float(e.y);
    }
    float tot = acc * rs_in[r * NNODES + d] + b2[r * NCLS + c];
    tot += __shfl_xor(tot, 16, 64);
    tot += __shfl_xor(tot, 32, 64);
    if (r == 0) out[(size_t)d * NCLS + c] = tot * 0.25f;
}

extern "C" void kernel_launch(void* const* d_in, const int* in_sizes, int n_in,
                              void* d_out, int out_size, void* d_ws, size_t ws_size,
                              hipStream_t stream) {
    const float* x  = (const float*)d_in[0];
    const float* W0 = (const float*)d_in[1];
    const float* b0 = (const float*)d_in[2];
    const float* W1 = (const float*)d_in[3];
    const float* b1 = (const float*)d_in[4];
    const float* W2 = (const float*)d_in[5];
    const float* b2 = (const float*)d_in[6];
    const int*   src = (const int*)d_in[7];
    const int*   dst = (const int*)d_in[8];
    float* out = (float*)d_out;

    // ---- workspace layout (~122 MB); 8B-aligned blocks first ----
    char* p = (char*)d_ws;
    int2* csrw   = (int2*)p;           p += sizeof(int2) * (size_t)NREL * NEDGE;
    float* hw    = (float*)p;          p += sizeof(float) * (size_t)NNODES * 64;
    int* cnt_out = (int*)p;            p += sizeof(int) * NREL * NNODES;
    int* cnt_in  = (int*)p;            p += sizeof(int) * NREL * NNODES;
    int* ofs     = (int*)p;            p += sizeof(int) * NREL * (NNODES + 1) + 12; // 16B align
    int* part    = (int*)p;            p += sizeof(int) * NREL * 128;
    float* rs_out = (float*)p;         p += sizeof(float) * NREL * NNODES;
    float* rs_in  = (float*)p;         p += sizeof(float) * NREL * NNODES;
    _Float16* Wt0h = (_Float16*)p;     p += sizeof(_Float16) * NREL * DHID * DHID;
    _Float16* Wt0l = (_Float16*)p;     p += sizeof(_Float16) * NREL * DHID * DHID;
    _Float16* Wt1h = (_Float16*)p;     p += sizeof(_Float16) * NREL * DHID * DHID;
    _Float16* Wt1l = (_Float16*)p;     p += sizeof(_Float16) * NREL * DHID * DHID;
    _Float16* W2h  = (_Float16*)p;     p += sizeof(_Float16) * 16 * 64 * 8;
    _Float16* W2l  = (_Float16*)p;     p += sizeof(_Float16) * 16 * 64 * 8;
    _Float16* xh   = (_Float16*)p;     p += sizeof(_Float16) * (size_t)NNODES * DHID;
    _Float16* h1   = (_Float16*)p;     p += sizeof(_Float16) * (size_t)NNODES * DHID;
    _Float16* h2   = (_Float16*)p;     p += sizeof(_Float16) * (size_t)NNODES * DHID;

    // ---- CSR + norms (once; shared by all layers) ----
    hipMemsetAsync(cnt_out, 0, 2ull * NREL * NNODES * sizeof(int), stream);
    dim3 eg((NEDGE + 255) / 256, NREL);
    edge_hist<<<eg, 256, 0, stream>>>(src, dst, cnt_out, cnt_in);
    rs_fin<<<(NREL * NNODES + 255) / 256, 256, 0, stream>>>(cnt_out, cnt_in, rs_out, rs_in);
    dim3 sg(SCANB, NREL);
    scan1<<<sg, 256, 0, stream>>>(cnt_in, part);
    scan2<<<NREL, 128, 0, stream>>>(part);
    scan3<<<sg, 256, 0, stream>>>(cnt_in, part, ofs);
    csr_fill<<<eg, 256, 0, stream>>>(src, dst, ofs, cnt_in, rs_out, csrw);

    // ---- weight splits + x conversion ----
    wsplit<<<256, 256, 0, stream>>>(W0, Wt0h, Wt0l);
    wsplit<<<256, 256, 0, stream>>>(W1, Wt1h, Wt1l);
    wsplit2<<<32, 256, 0, stream>>>(W2, W2h, W2l);
    xcvt<<<(NNODES * DHID / 4 + 255) / 256, 256, 0, stream>>>(x, xh);

    int gb = (NNODES + 63) / 64;

    // ---- layers 0/1: fused gather+GEMM (fp16 features) ----
    gconv<<<gb, 512, 0, stream>>>(xh, rs_in, ofs, csrw, Wt0h, Wt0l, b0, h1);
    gconv<<<gb, 512, 0, stream>>>(h1, rs_in, ofs, csrw, Wt1h, Wt1l, b1, h2);

    // ---- layer 2: one MFMA GEMM (all relations), gather+epilogue ----
    gemm64h<<<gb, 256, 0, stream>>>(h2, W2h, W2l, hw);
    l2_out<<<(NNODES + 3) / 4, 256, 0, stream>>>(hw, ofs, csrw, rs_in, b2, out);
}

// Round 9
// 686.823 us; speedup vs baseline: 2.4781x; 1.0001x over previous
//
#include <hip/hip_runtime.h>

// RGCN: 3× HeteroGraphConv(mean over R=4 relations of GraphConv(norm='both')).
// R8 (resubmit; R8 bench was GPUAcquisitionTimeout — never measured):
// gconv gather = 4 rows x 2-deep interleaved batches (8 f16x8 + 8 int2
// loads in flight per thread, vs 4 in R7) -- gconv is MLP-bound (R7: halving
// bytes did nothing, 4x MLP gave 1.8x). hw -> fp16 (l2_out reads 32B/edge),
// l2_out 4-deep edge loop. Everything else unchanged from R7.

#define NNODES 100000
#define NEDGE  400000
#define NREL   4
#define DHID   128
#define NCLS   16
#define SCANB  98            // ceil(N / 1024)

typedef _Float16 f16x8 __attribute__((ext_vector_type(8)));
typedef _Float16 f16x4 __attribute__((ext_vector_type(4)));
typedef float    f32x4 __attribute__((ext_vector_type(4)));

// ---------------- degree histograms (global atomics; ~124us known) ----------------
__global__ void edge_hist(const int* __restrict__ src, const int* __restrict__ dst,
                          int* __restrict__ cnt_out, int* __restrict__ cnt_in) {
    int e = blockIdx.x * 256 + threadIdx.x;
    int r = blockIdx.y;
    if (e < NEDGE) {
        atomicAdd(&cnt_out[r * NNODES + src[r * NEDGE + e]], 1);
        atomicAdd(&cnt_in [r * NNODES + dst[r * NEDGE + e]], 1);
    }
}

__global__ void rs_fin(const int* __restrict__ cnt_out, const int* __restrict__ cnt_in,
                       float* __restrict__ rs_out, float* __restrict__ rs_in) {
    int i = blockIdx.x * 256 + threadIdx.x;
    if (i < NREL * NNODES) {
        rs_out[i] = rsqrtf(fmaxf((float)cnt_out[i], 1.0f));
        rs_in [i] = rsqrtf(fmaxf((float)cnt_in [i], 1.0f));
    }
}

// ---------------- 2-level exclusive scan of cnt_in -> ofs ----------------
__global__ void scan1(const int* __restrict__ cnt, int* __restrict__ part) {
    __shared__ int sh[256];
    int r = blockIdx.y, b = blockIdx.x, tid = threadIdx.x;
    int n0 = b * 1024 + tid * 4;
    int s = 0;
#pragma unroll
    for (int j = 0; j < 4; ++j) {
        int n = n0 + j;
        s += (n < NNODES) ? cnt[r * NNODES + n] : 0;
    }
    sh[tid] = s; __syncthreads();
    for (int off = 128; off > 0; off >>= 1) {
        if (tid < off) sh[tid] += sh[tid + off];
        __syncthreads();
    }
    if (tid == 0) part[r * SCANB + b] = sh[0];
}

__global__ void scan2(int* __restrict__ part) {
    __shared__ int sh[128];
    int r = blockIdx.x, tid = threadIdx.x;
    int v = (tid < SCANB) ? part[r * SCANB + tid] : 0;
    sh[tid] = v; __syncthreads();
    for (int off = 1; off < 128; off <<= 1) {
        int t = (tid >= off) ? sh[tid - off] : 0;
        __syncthreads();
        sh[tid] += t;
        __syncthreads();
    }
    if (tid < SCANB) part[r * SCANB + tid] = sh[tid] - v;  // exclusive
}

__global__ void scan3(const int* __restrict__ cnt, const int* __restrict__ part,
                      int* __restrict__ ofs) {
    __shared__ int sh[256];
    int r = blockIdx.y, b = blockIdx.x, tid = threadIdx.x;
    int n0 = b * 1024 + tid * 4;
    int v[4];
    int tsum = 0;
#pragma unroll
    for (int j = 0; j < 4; ++j) {
        int n = n0 + j;
        v[j] = (n < NNODES) ? cnt[r * NNODES + n] : 0;
        tsum += v[j];
    }
    sh[tid] = tsum; __syncthreads();
    for (int off = 1; off < 256; off <<= 1) {
        int t = (tid >= off) ? sh[tid - off] : 0;
        __syncthreads();
        sh[tid] += t;
        __syncthreads();
    }
    int base = part[r * SCANB + b] + sh[tid] - tsum;
#pragma unroll
    for (int j = 0; j < 4; ++j) {
        int n = n0 + j;
        if (n < NNODES) ofs[r * (NNODES + 1) + n] = base;
        base += v[j];
    }
    if (b == 0 && tid == 0) ofs[r * (NNODES + 1) + NNODES] = NEDGE;
}

// fill CSR with edge weight w = rs_out[src] folded in
__global__ void csr_fill(const int* __restrict__ src, const int* __restrict__ dst,
                         const int* __restrict__ ofs, int* __restrict__ cnt_in,
                         const float* __restrict__ rs_out, int2* __restrict__ csrw) {
    int e = blockIdx.x * 256 + threadIdx.x;
    int r = blockIdx.y;
    if (e < NEDGE) {
        int s = src[r * NEDGE + e], d = dst[r * NEDGE + e];
        int k = atomicSub(&cnt_in[r * NNODES + d], 1) - 1;
        int2 ew;
        ew.x = s;
        ew.y = __float_as_int(rs_out[r * NNODES + s]);
        csrw[(size_t)r * NEDGE + ofs[r * (NNODES + 1) + d] + k] = ew;
    }
}

// ---------------- W pre-split into MFMA frag layout ----------------
// Wt[((r*16 + k>>3)*128 + c)*8 + (k&7)], value W[r][k][c] split hi/lo.
__global__ void wsplit(const float* __restrict__ W, _Float16* __restrict__ whi,
                       _Float16* __restrict__ wlo) {
    int idx = blockIdx.x * 256 + threadIdx.x;   // 4*128*128 = 65536
    int c = idx & 127, k = (idx >> 7) & 127, r = idx >> 14;
    float w = W[(size_t)r * 16384 + k * 128 + c];
    _Float16 hi = (_Float16)w;
    size_t o = (((size_t)r * 16 + (k >> 3)) * 128 + c) * 8 + (k & 7);
    whi[o] = hi;
    wlo[o] = (_Float16)(w - (float)hi);
}

// W2 [4][128][16] -> frag layout [k>>3][r*16+c][k&7], hi/lo
__global__ void wsplit2(const float* __restrict__ W2, _Float16* __restrict__ wh,
                        _Float16* __restrict__ wl) {
    int idx = blockIdx.x * 256 + threadIdx.x;   // 8192
    if (idx < NREL * DHID * NCLS) {
        int c = idx & 15, k = (idx >> 4) & 127, r = idx >> 11;
        float w = W2[idx];
        _Float16 hi = (_Float16)w;
        size_t o = ((size_t)(k >> 3) * 64 + r * 16 + c) * 8 + (k & 7);
        wh[o] = hi;
        wl[o] = (_Float16)(w - (float)hi);
    }
}

// ---------------- x -> fp16 plane ----------------
__global__ void xcvt(const float* __restrict__ x, _Float16* __restrict__ xh) {
    int i = blockIdx.x * 256 + threadIdx.x;     // over N*DHID/4
    if (i < NNODES * DHID / 4) {
        float4 v = ((const float4*)x)[i];
        f16x4 h = {(_Float16)v.x, (_Float16)v.y, (_Float16)v.z, (_Float16)v.w};
        *(f16x4*)&xh[(size_t)i * 4] = h;
    }
}

// ---------------- fused GraphConv layer: gather(4-row interleave) + MFMA ----------------
__global__ __launch_bounds__(512) void gconv(
        const _Float16* __restrict__ Hh, const float* __restrict__ rs_in,
        const int* __restrict__ ofs, const int2* __restrict__ csrw,
        const _Float16* __restrict__ Wt_hi, const _Float16* __restrict__ Wt_lo,
        const float* __restrict__ bias, _Float16* __restrict__ outH) {
    __shared__ _Float16 lhi[4 * 16 * 67 * 8];   // [rel][kblk][row+skew][8]  68.6KB
    __shared__ int lofs[NREL][65];
    int tid = threadIdx.x;
    int lane = tid & 63, wid = tid >> 6;
    int wm = wid >> 2, wn = wid & 3;        // 2x4 waves: wave tile 32 rows x 32 cols
    int r15 = lane & 15;
    int row0 = blockIdx.x * 64;

    if (tid < 4 * 65) {
        int rel = tid / 65, i = tid - rel * 65;
        int n = row0 + i;
        lofs[rel][i] = (n <= NNODES) ? ofs[rel * (NNODES + 1) + n] : NEDGE;
    }
    __syncthreads();

    // ---- gather ALL 4 rels: 16 lanes/row; 4 rows x 2-deep interleaved ----
    {
        int lane16 = tid & 15;          // feature block: feats lane16*8 .. +7
        int grp    = tid >> 4;          // 0..31
        const _Float16* hb = Hh + (size_t)lane16 * 8;
#pragma unroll
        for (int s = 0; s < 2; ++s) {
            int rel[4], rr[4], ii[4], ee[4];
            float acc[4][8] = {};
#pragma unroll
            for (int k = 0; k < 4; ++k) {
                int u = grp + s * 128 + k * 32;
                rel[k] = u >> 6; rr[k] = u & 63;
                ii[k] = lofs[rel[k]][rr[k]];
                ee[k] = lofs[rel[k]][rr[k] + 1];
                if (row0 + rr[k] >= NNODES) { ii[k] = 0; ee[k] = 0; }
            }
            // main: 8 int2 + 8 f16x8 loads in flight
            while (ii[0] + 2 <= ee[0] && ii[1] + 2 <= ee[1] &&
                   ii[2] + 2 <= ee[2] && ii[3] + 2 <= ee[3]) {
                int2 ed[4][2];
                f16x8 v[4][2];
#pragma unroll
                for (int k = 0; k < 4; ++k) {
                    const int2* cw = csrw + (size_t)rel[k] * NEDGE;
                    ed[k][0] = cw[ii[k]];
                    ed[k][1] = cw[ii[k] + 1];
                }
#pragma unroll
                for (int k = 0; k < 4; ++k) {
                    v[k][0] = *(const f16x8*)(hb + (size_t)ed[k][0].x * DHID);
                    v[k][1] = *(const f16x8*)(hb + (size_t)ed[k][1].x * DHID);
                }
#pragma unroll
                for (int k = 0; k < 4; ++k) {
                    float w0 = __int_as_float(ed[k][0].y);
                    float w1 = __int_as_float(ed[k][1].y);
#pragma unroll
                    for (int j = 0; j < 8; ++j)
                        acc[k][j] += (float)v[k][0][j] * w0 + (float)v[k][1][j] * w1;
                    ii[k] += 2;
                }
            }
            // drains: 4-deep then scalar, per row; then scale + LDS write
#pragma unroll
            for (int k = 0; k < 4; ++k) {
                const int2* cw = csrw + (size_t)rel[k] * NEDGE;
                int i = ii[k], end = ee[k];
                for (; i + 4 <= end; i += 4) {
                    int2 e0 = cw[i], e1 = cw[i + 1], e2 = cw[i + 2], e3 = cw[i + 3];
                    f16x8 v0 = *(const f16x8*)(hb + (size_t)e0.x * DHID);
                    f16x8 v1 = *(const f16x8*)(hb + (size_t)e1.x * DHID);
                    f16x8 v2 = *(const f16x8*)(hb + (size_t)e2.x * DHID);
                    f16x8 v3 = *(const f16x8*)(hb + (size_t)e3.x * DHID);
                    float w0 = __int_as_float(e0.y), w1 = __int_as_float(e1.y);
                    float w2 = __int_as_float(e2.y), w3 = __int_as_float(e3.y);
#pragma unroll
                    for (int j = 0; j < 8; ++j)
                        acc[k][j] += ((float)v0[j] * w0 + (float)v1[j] * w1)
                                   + ((float)v2[j] * w2 + (float)v3[j] * w3);
                }
                for (; i < end; ++i) {
                    int2 e = cw[i];
                    f16x8 v = *(const f16x8*)(hb + (size_t)e.x * DHID);
                    float w = __int_as_float(e.y);
#pragma unroll
                    for (int j = 0; j < 8; ++j) acc[k][j] += (float)v[j] * w;
                }
                int row = row0 + rr[k];
                float rv = (row < NNODES) ? rs_in[rel[k] * NNODES + row] : 0.f;
                f16x8 o;
#pragma unroll
                for (int j = 0; j < 8; ++j) o[j] = (_Float16)(acc[k][j] * rv);
                *(f16x8*)&lhi[(((rel[k] * 16 + lane16) * 67) + rr[k]) * 8] = o;
            }
        }
    }
    __syncthreads();

    // ---- MFMA: 4 relations back-to-back, K=128 each, 2-term (W hi/lo) ----
    f32x4 oacc[2][2] = {};
    int kb = lane >> 4;
    int rbase = wm * 32 + r15;
    int c = wn * 32 + r15;
    for (int rel = 0; rel < NREL; ++rel) {
        f32x4 acc4[2][2] = {};
#pragma unroll
        for (int kt = 0; kt < 4; ++kt) {
            const _Float16* bh = Wt_hi + ((size_t)rel * 16 + kt * 4 + kb) * 128 * 8;
            const _Float16* bl = Wt_lo + ((size_t)rel * 16 + kt * 4 + kb) * 128 * 8;
            f16x8 wh[2], wl[2], ah[2];
#pragma unroll
            for (int nf = 0; nf < 2; ++nf) {
                wh[nf] = *(const f16x8*)(bh + (size_t)(c + nf * 16) * 8);
                wl[nf] = *(const f16x8*)(bl + (size_t)(c + nf * 16) * 8);
            }
#pragma unroll
            for (int mf = 0; mf < 2; ++mf) {
                int li = (((rel * 16 + kt * 4 + kb) * 67) + rbase + mf * 16) * 8;
                ah[mf] = *(const f16x8*)&lhi[li];
            }
#pragma unroll
            for (int nf = 0; nf < 2; ++nf)
#pragma unroll
                for (int mf = 0; mf < 2; ++mf) {
                    acc4[mf][nf] = __builtin_amdgcn_mfma_f32_16x16x32_f16(ah[mf], wh[nf], acc4[mf][nf], 0, 0, 0);
                    acc4[mf][nf] = __builtin_amdgcn_mfma_f32_16x16x32_f16(ah[mf], wl[nf], acc4[mf][nf], 0, 0, 0);
                }
        }
        const float* b = bias + rel * DHID;
#pragma unroll
        for (int mf = 0; mf < 2; ++mf)
#pragma unroll
            for (int nf = 0; nf < 2; ++nf) {
                float bb = b[wn * 32 + nf * 16 + r15];
#pragma unroll
                for (int i = 0; i < 4; ++i)
                    oacc[mf][nf][i] += fmaxf(acc4[mf][nf][i] + bb, 0.f);
            }
    }

    // ---- epilogue: C/D layout col=lane&15, row=(lane>>4)*4+i; write fp16 h ----
    int rsub = (lane >> 4) * 4;
#pragma unroll
    for (int mf = 0; mf < 2; ++mf)
#pragma unroll
        for (int i = 0; i < 4; ++i) {
            int row = row0 + wm * 32 + mf * 16 + rsub + i;
            if (row < NNODES) {
#pragma unroll
                for (int nf = 0; nf < 2; ++nf) {
                    int cc = wn * 32 + nf * 16 + r15;
                    outH[(size_t)row * DHID + cc] = (_Float16)(oacc[mf][nf][i] * 0.25f);
                }
            }
        }
}

// ---------------- layer 2 GEMM: hw(fp16) = h2(fp16) @ [W2_0|..|W2_3] ----------------
__global__ __launch_bounds__(256) void gemm64h(const _Float16* __restrict__ Hh,
                                               const _Float16* __restrict__ W2h,
                                               const _Float16* __restrict__ W2l,
                                               _Float16* __restrict__ hw) {
    int tid = threadIdx.x, lane = tid & 63, wid = tid >> 6;
    int row0 = blockIdx.x * 64;
    int arow = row0 + wid * 16 + (lane & 15);
    int kb = lane >> 4;
    f32x4 acc[4] = {};
#pragma unroll
    for (int kt = 0; kt < 4; ++kt) {
        f16x8 a = {};
        if (arow < NNODES)
            a = *(const f16x8*)&Hh[(size_t)arow * DHID + kt * 32 + kb * 8];
        const _Float16* bh = W2h + ((size_t)(kt * 4 + kb) * 64) * 8;
        const _Float16* bl = W2l + ((size_t)(kt * 4 + kb) * 64) * 8;
#pragma unroll
        for (int nf = 0; nf < 4; ++nf) {
            f16x8 wh = *(const f16x8*)(bh + (size_t)(nf * 16 + (lane & 15)) * 8);
            f16x8 wl = *(const f16x8*)(bl + (size_t)(nf * 16 + (lane & 15)) * 8);
            acc[nf] = __builtin_amdgcn_mfma_f32_16x16x32_f16(a, wh, acc[nf], 0, 0, 0);
            acc[nf] = __builtin_amdgcn_mfma_f32_16x16x32_f16(a, wl, acc[nf], 0, 0, 0);
        }
    }
    int rsub = (lane >> 4) * 4;
#pragma unroll
    for (int nf = 0; nf < 4; ++nf)
#pragma unroll
        for (int i = 0; i < 4; ++i) {
            int row = row0 + wid * 16 + rsub + i;
            if (row < NNODES)
                hw[(size_t)row * 64 + nf * 16 + (lane & 15)] = (_Float16)acc[nf][i];
        }
}

// ---------------- layer-2 gather+epilogue: 64 lanes/dst (16 per rel) ----------------
__global__ __launch_bounds__(256) void l2_out(const _Float16* __restrict__ hw,
                                              const int* __restrict__ ofs,
                                              const int2* __restrict__ csrw,
                                              const float* __restrict__ rs_in,
                                              const float* __restrict__ b2,
                                              float* __restrict__ out) {
    int t = threadIdx.x;
    int d = blockIdx.x * 4 + (t >> 6);
    int lane = t & 63;
    int r = lane >> 4;          // relation
    int c = lane & 15;          // class
    if (d >= NNODES) return;
    int i   = ofs[r * (NNODES + 1) + d];
    int end = ofs[r * (NNODES + 1) + d + 1];
    const int2* cw = csrw + (size_t)r * NEDGE;
    float acc = 0.f;
    for (; i + 4 <= end; i += 4) {
        int2 e0 = cw[i], e1 = cw[i + 1], e2 = cw[i + 2], e3 = cw[i + 3];
        float v0 = (float)hw[(size_t)e0.x * 64 + r * NCLS + c];
        float v1 = (float)hw[(size_t)e1.x * 64 + r * NCLS + c];
        float v2 = (float)hw[(size_t)e2.x * 64 + r * NCLS + c];
        float v3 = (float)hw[(size_t)e3.x * 64 + r * NCLS + c];
        acc += v0 * __int_as_float(e0.y) + v1 * __int_as_float(e1.y)
             + v2 * __int_as_float(e2.y) + v3 * __int_as_float(e3.y);
    }
    for (; i < end; ++i) {
        int2 e = cw[i];
        acc += (float)hw[(size_t)e.x * 64 + r * NCLS + c] * __int_as_float(e.y);
    }
    float tot = acc * rs_in[r * NNODES + d] + b2[r * NCLS + c];
    tot += __shfl_xor(tot, 16, 64);
    tot += __shfl_xor(tot, 32, 64);
    if (r == 0) out[(size_t)d * NCLS + c] = tot * 0.25f;
}

extern "C" void kernel_launch(void* const* d_in, const int* in_sizes, int n_in,
                              void* d_out, int out_size, void* d_ws, size_t ws_size,
                              hipStream_t stream) {
    const float* x  = (const float*)d_in[0];
    const float* W0 = (const float*)d_in[1];
    const float* b0 = (const float*)d_in[2];
    const float* W1 = (const float*)d_in[3];
    const float* b1 = (const float*)d_in[4];
    const float* W2 = (const float*)d_in[5];
    const float* b2 = (const float*)d_in[6];
    const int*   src = (const int*)d_in[7];
    const int*   dst = (const int*)d_in[8];
    float* out = (float*)d_out;

    // ---- workspace layout; 8B-aligned blocks first ----
    char* p = (char*)d_ws;
    int2* csrw   = (int2*)p;           p += sizeof(int2) * (size_t)NREL * NEDGE;
    int* cnt_out = (int*)p;            p += sizeof(int) * NREL * NNODES;
    int* cnt_in  = (int*)p;            p += sizeof(int) * NREL * NNODES;
    int* ofs     = (int*)p;            p += sizeof(int) * NREL * (NNODES + 1) + 12; // 16B align
    int* part    = (int*)p;            p += sizeof(int) * NREL * 128;
    float* rs_out = (float*)p;         p += sizeof(float) * NREL * NNODES;
    float* rs_in  = (float*)p;         p += sizeof(float) * NREL * NNODES;
    _Float16* Wt0h = (_Float16*)p;     p += sizeof(_Float16) * NREL * DHID * DHID;
    _Float16* Wt0l = (_Float16*)p;     p += sizeof(_Float16) * NREL * DHID * DHID;
    _Float16* Wt1h = (_Float16*)p;     p += sizeof(_Float16) * NREL * DHID * DHID;
    _Float16* Wt1l = (_Float16*)p;     p += sizeof(_Float16) * NREL * DHID * DHID;
    _Float16* W2h  = (_Float16*)p;     p += sizeof(_Float16) * 16 * 64 * 8;
    _Float16* W2l  = (_Float16*)p;     p += sizeof(_Float16) * 16 * 64 * 8;
    _Float16* xh   = (_Float16*)p;     p += sizeof(_Float16) * (size_t)NNODES * DHID;
    _Float16* h1   = (_Float16*)p;     p += sizeof(_Float16) * (size_t)NNODES * DHID;
    _Float16* h2   = (_Float16*)p;     p += sizeof(_Float16) * (size_t)NNODES * DHID;
    _Float16* hw   = (_Float16*)p;     p += sizeof(_Float16) * (size_t)NNODES * 64;

    // ---- CSR + norms (once; shared by all layers) ----
    hipMemsetAsync(cnt_out, 0, 2ull * NREL * NNODES * sizeof(int), stream);
    dim3 eg((NEDGE + 255) / 256, NREL);
    edge_hist<<<eg, 256, 0, stream>>>(src, dst, cnt_out, cnt_in);
    rs_fin<<<(NREL * NNODES + 255) / 256, 256, 0, stream>>>(cnt_out, cnt_in, rs_out, rs_in);
    dim3 sg(SCANB, NREL);
    scan1<<<sg, 256, 0, stream>>>(cnt_in, part);
    scan2<<<NREL, 128, 0, stream>>>(part);
    scan3<<<sg, 256, 0, stream>>>(cnt_in, part, ofs);
    csr_fill<<<eg, 256, 0, stream>>>(src, dst, ofs, cnt_in, rs_out, csrw);

    // ---- weight splits + x conversion ----
    wsplit<<<256, 256, 0, stream>>>(W0, Wt0h, Wt0l);
    wsplit<<<256, 256, 0, stream>>>(W1, Wt1h, Wt1l);
    wsplit2<<<32, 256, 0, stream>>>(W2, W2h, W2l);
    xcvt<<<(NNODES * DHID / 4 + 255) / 256, 256, 0, stream>>>(x, xh);

    int gb = (NNODES + 63) / 64;

    // ---- layers 0/1: fused gather+GEMM (fp16 features) ----
    gconv<<<gb, 512, 0, stream>>>(xh, rs_in, ofs, csrw, Wt0h, Wt0l, b0, h1);
    gconv<<<gb, 512, 0, stream>>>(h1, rs_in, ofs, csrw, Wt1h, Wt1l, b1, h2);

    // ---- layer 2: one MFMA GEMM (all relations), gather+epilogue ----
    gemm64h<<<gb, 256, 0, stream>>>(h2, W2h, W2l, hw);
    l2_out<<<(NNODES + 3) / 4, 256, 0, stream>>>(hw, ofs, csrw, rs_in, b2, out);
}